// Round 3
// baseline (1377.108 us; speedup 1.0000x reference)
//
#include <hip/hip_runtime.h>

#define NN 100000
#define NE 1600000

typedef unsigned int uint32;
typedef float f32x2 __attribute__((ext_vector_type(2)));

__device__ inline unsigned short f2bf(float f) {
    uint32 u = __float_as_uint(f);
    u += 0x7FFFu + ((u >> 16) & 1u);      // round to nearest even
    return (unsigned short)(u >> 16);
}
__device__ inline float bflo(uint32 v) { return __uint_as_float(v << 16); }
__device__ inline float bfhi(uint32 v) { return __uint_as_float(v & 0xFFFF0000u); }

// ---------------- CSR build ----------------

__global__ void count_k(const int* __restrict__ dst, int* __restrict__ cnt) {
    int e = blockIdx.x * 256 + threadIdx.x;
    if (e < NE) atomicAdd(&cnt[dst[e]], 1);
}

__global__ void scan_partial_k(const int* __restrict__ cnt, int* __restrict__ part) {
    __shared__ int sh[256];
    int t = threadIdx.x;
    int base = blockIdx.x * 1024 + t * 4;
    int s = 0;
#pragma unroll
    for (int j = 0; j < 4; ++j) { int i = base + j; if (i < NN) s += cnt[i]; }
    sh[t] = s;
    __syncthreads();
    for (int d = 128; d > 0; d >>= 1) { if (t < d) sh[t] += sh[t + d]; __syncthreads(); }
    if (t == 0) part[blockIdx.x] = sh[0];
}

__global__ void scan_top_k(int* part, int nb) {
    if (threadIdx.x == 0 && blockIdx.x == 0) {
        int run = 0;
        for (int i = 0; i < nb; ++i) { int v = part[i]; part[i] = run; run += v; }
    }
}

__global__ void scan_offsets_k(const int* __restrict__ cnt, const int* __restrict__ part,
                               int* __restrict__ offs, int* __restrict__ cur) {
    __shared__ int sh[256];
    int t = threadIdx.x;
    int base = blockIdx.x * 1024 + t * 4;
    int v[4]; int s = 0;
#pragma unroll
    for (int j = 0; j < 4; ++j) { int i = base + j; v[j] = (i < NN) ? cnt[i] : 0; s += v[j]; }
    sh[t] = s;
    __syncthreads();
    if (t == 0) {
        int run = 0;
        for (int i = 0; i < 256; ++i) { int tmp = sh[i]; sh[i] = run; run += tmp; }
    }
    __syncthreads();
    int excl = part[blockIdx.x] + sh[t];
#pragma unroll
    for (int j = 0; j < 4; ++j) {
        int i = base + j;
        if (i < NN) { offs[i] = excl; cur[i] = excl; }
        excl += v[j];
    }
    if (blockIdx.x == 0 && t == 0) offs[NN] = NE;
}

__global__ void dinv_k(const int* __restrict__ cnt, float* __restrict__ dinv) {
    int i = blockIdx.x * 256 + threadIdx.x;
    if (i < NN) dinv[i] = rsqrtf((float)(cnt[i] + 1));
}

__global__ void fill_k(const int* __restrict__ src, const int* __restrict__ dst,
                       int* __restrict__ cur, int* __restrict__ csrc) {
    int e = blockIdx.x * 256 + threadIdx.x;
    if (e < NE) {
        int d = dst[e];
        int p = atomicAdd(&cur[d], 1);
        csrc[p] = src[e];
    }
}

// ---------------- degree sort (counting sort, 256 bins) ----------------

__global__ void hist_k(const int* __restrict__ cnt, int* __restrict__ hist) {
    int i = blockIdx.x * 256 + threadIdx.x;
    if (i < NN) atomicAdd(&hist[min(cnt[i], 255)], 1);
}

__global__ void hscan_k(const int* __restrict__ hist, int* __restrict__ hcur) {
    if (threadIdx.x == 0 && blockIdx.x == 0) {
        int run = 0;
        for (int i = 0; i < 256; ++i) { int v = hist[i]; hcur[i] = run; run += v; }
    }
}

__global__ void scatter_k(const int* __restrict__ cnt, int* __restrict__ hcur,
                          int* __restrict__ porder) {
    int i = blockIdx.x * 256 + threadIdx.x;
    if (i < NN) {
        int b = min(cnt[i], 255);
        int p = atomicAdd(&hcur[b], 1);
        porder[p] = i;
    }
}

// ------ dense GEMM: HS = dinv[row] * act(X) @ W, bf16, channel-chunked ------
// Output layout: chunk c (16 ch) at hs[c*NN*8 + row*8 + u], u = channel pair.
// AFF=1: apply per-channel relu(sc*x+sh) (fused GraphNorm+ReLU) while staging.

template <int AFF>
__global__ __launch_bounds__(256) void gemm128_k(const float* __restrict__ X,
                                                 const float* __restrict__ W,
                                                 const float* __restrict__ par,
                                                 const float* __restrict__ dinv,
                                                 uint32* __restrict__ HS) {
    __shared__ float xs[64][132];   // +4 pad: breaks power-of-2 bank stride
    int t = threadIdx.x;
    int row0 = blockIdx.x * 64;
    for (int i = t; i < 64 * 32; i += 256) {
        int r = i >> 5, c4 = i & 31;
        int row = row0 + r;
        float4 v = make_float4(0.f, 0.f, 0.f, 0.f);
        if (row < NN) v = ((const float4*)(X + (size_t)row * 128))[c4];
        if (AFF) {
            int c = c4 * 4;
            v.x = fmaxf(0.f, fmaf(par[c + 0], v.x, par[128 + c + 0]));
            v.y = fmaxf(0.f, fmaf(par[c + 1], v.y, par[128 + c + 1]));
            v.z = fmaxf(0.f, fmaf(par[c + 2], v.z, par[128 + c + 2]));
            v.w = fmaxf(0.f, fmaf(par[c + 3], v.w, par[128 + c + 3]));
        }
        *(float4*)&xs[r][c4 * 4] = v;
    }
    __syncthreads();
    int tx = t & 15, ty = t >> 4;      // 16 col-groups x 16 row-groups
    float acc[4][8];
#pragma unroll
    for (int r = 0; r < 4; ++r)
#pragma unroll
        for (int j = 0; j < 8; ++j) acc[r][j] = 0.f;

    for (int k = 0; k < 128; ++k) {
        float4 w0 = *(const float4*)(W + k * 128 + tx * 8);
        float4 w1 = *(const float4*)(W + k * 128 + tx * 8 + 4);
        float xv[4];
#pragma unroll
        for (int r = 0; r < 4; ++r) xv[r] = xs[ty * 4 + r][k];
#pragma unroll
        for (int r = 0; r < 4; ++r) {
            acc[r][0] = fmaf(xv[r], w0.x, acc[r][0]);
            acc[r][1] = fmaf(xv[r], w0.y, acc[r][1]);
            acc[r][2] = fmaf(xv[r], w0.z, acc[r][2]);
            acc[r][3] = fmaf(xv[r], w0.w, acc[r][3]);
            acc[r][4] = fmaf(xv[r], w1.x, acc[r][4]);
            acc[r][5] = fmaf(xv[r], w1.y, acc[r][5]);
            acc[r][6] = fmaf(xv[r], w1.z, acc[r][6]);
            acc[r][7] = fmaf(xv[r], w1.w, acc[r][7]);
        }
    }
    int chunk = tx >> 1;           // channels tx*8.. belong to chunk tx/2
    int ub = (tx & 1) * 4;         // uint offset within chunk row
#pragma unroll
    for (int r = 0; r < 4; ++r) {
        int row = row0 + ty * 4 + r;
        if (row < NN) {
            float d = dinv[row];
            uint4 o;
            o.x = (uint32)f2bf(d * acc[r][0]) | ((uint32)f2bf(d * acc[r][1]) << 16);
            o.y = (uint32)f2bf(d * acc[r][2]) | ((uint32)f2bf(d * acc[r][3]) << 16);
            o.z = (uint32)f2bf(d * acc[r][4]) | ((uint32)f2bf(d * acc[r][5]) << 16);
            o.w = (uint32)f2bf(d * acc[r][6]) | ((uint32)f2bf(d * acc[r][7]) << 16);
            *(uint4*)(HS + (size_t)chunk * NN * 8 + (size_t)row * 8 + ub) = o;
        }
    }
}

// -------- edge aggregation: chunked gather (L2-resident per XCD) + stats ----
// out[i,ch] = dinv[i]*( sum_e hs[src,ch] + hs[i,ch] ) + bias[ch]
// blockIdx.x & 7 = chunk -> pinned to one XCD by round-robin dispatch.
// 8 threads per node (u = channel-pair), 32 nodes per block.
// Also accumulates per-channel sum / sumsq of out into stats (GraphNorm).

__global__ __launch_bounds__(256) void aggregate_k(const uint32* __restrict__ hs,
                                                   const int* __restrict__ offs,
                                                   const int* __restrict__ csrc,
                                                   const int* __restrict__ porder,
                                                   const float* __restrict__ dinv,
                                                   const float* __restrict__ bias,
                                                   float* __restrict__ out,
                                                   float* __restrict__ stats) {
    __shared__ float4 sh[256];
    int t = threadIdx.x;
    int chunk = blockIdx.x & 7;
    int tile = blockIdx.x >> 3;
    int g = t >> 3, u = t & 7;
    int node = porder[tile * 32 + g];
    int beg = offs[node], end = offs[node + 1];
    float di = dinv[node];
    const uint32* hc = hs + (size_t)chunk * NN * 8;
    uint32 sv = hc[(size_t)node * 8 + u];          // self (already dinv-scaled)
    float a0 = bflo(sv), a1 = bfhi(sv);
    int e = beg;
    for (; e + 3 < end; e += 4) {
        int s0 = __builtin_nontemporal_load(csrc + e);
        int s1 = __builtin_nontemporal_load(csrc + e + 1);
        int s2 = __builtin_nontemporal_load(csrc + e + 2);
        int s3 = __builtin_nontemporal_load(csrc + e + 3);
        uint32 v0 = hc[(size_t)s0 * 8 + u];
        uint32 v1 = hc[(size_t)s1 * 8 + u];
        uint32 v2 = hc[(size_t)s2 * 8 + u];
        uint32 v3 = hc[(size_t)s3 * 8 + u];
        a0 += (bflo(v0) + bflo(v1)) + (bflo(v2) + bflo(v3));
        a1 += (bfhi(v0) + bfhi(v1)) + (bfhi(v2) + bfhi(v3));
    }
    for (; e < end; ++e) {
        int s0 = __builtin_nontemporal_load(csrc + e);
        uint32 v0 = hc[(size_t)s0 * 8 + u];
        a0 += bflo(v0);
        a1 += bfhi(v0);
    }
    float2 bb = ((const float2*)bias)[chunk * 8 + u];
    float o0 = fmaf(di, a0, bb.x);
    float o1 = fmaf(di, a1, bb.y);
    f32x2 ov; ov.x = o0; ov.y = o1;
    __builtin_nontemporal_store(ov, (f32x2*)out + (size_t)node * 64 + chunk * 8 + u);

    // fused GraphNorm stats: reduce over the 32 nodes of this block
    sh[t] = make_float4(o0, o1, o0 * o0, o1 * o1);
    __syncthreads();
    for (int st = 128; st >= 8; st >>= 1) {
        if (t < st) {
            float4 a = sh[t], b = sh[t + st];
            sh[t] = make_float4(a.x + b.x, a.y + b.y, a.z + b.z, a.w + b.w);
        }
        __syncthreads();
    }
    if (t < 8) {
        float4 v = sh[t];
        int ch = chunk * 16 + t * 2;
        atomicAdd(&stats[ch], v.x);
        atomicAdd(&stats[ch + 1], v.y);
        atomicAdd(&stats[128 + ch], v.z);
        atomicAdd(&stats[128 + ch + 1], v.w);
    }
}

__global__ void gnparams_k(const float* __restrict__ stats, const float* __restrict__ w,
                           const float* __restrict__ b, const float* __restrict__ a,
                           float* __restrict__ par) {
    int c = threadIdx.x;
    if (c < 128) {
        float m = stats[c] * (1.0f / NN);
        float ex2 = stats[128 + c] * (1.0f / NN);
        float ac = a[c];
        // var of (x - a*m): E[x^2] - 2*a*m^2 + a^2*m^2
        float var = ex2 - 2.0f * ac * m * m + ac * ac * m * m;
        float sc = w[c] * rsqrtf(var + 1e-5f);
        par[c] = sc;                       // scale
        par[128 + c] = b[c] - sc * ac * m; // shift
    }
}

// ---------------- head: out = [x, relu(gn2(x2))] @ Wh + bh ----------------

__global__ __launch_bounds__(256) void final_k(const float* __restrict__ x,
                                               const float* __restrict__ x2,
                                               const float* __restrict__ par,
                                               const float* __restrict__ Wh,
                                               const float* __restrict__ bh,
                                               float* __restrict__ out) {
    __shared__ float wl[256][16];
    int t = threadIdx.x;
    for (int i = t; i < 256 * 16; i += 256) wl[i >> 4][i & 15] = Wh[i];
    __syncthreads();
    int row = blockIdx.x * 16 + (t >> 4);
    int o = t & 15;
    if (row >= NN) return;
    const float4* xp = (const float4*)(x + (size_t)row * 128);
    const float4* x2p = (const float4*)(x2 + (size_t)row * 128);
    float acc = bh[o];
#pragma unroll
    for (int k4 = 0; k4 < 32; ++k4) {
        float4 v = xp[k4];
        acc = fmaf(v.x, wl[k4 * 4 + 0][o], acc);
        acc = fmaf(v.y, wl[k4 * 4 + 1][o], acc);
        acc = fmaf(v.z, wl[k4 * 4 + 2][o], acc);
        acc = fmaf(v.w, wl[k4 * 4 + 3][o], acc);
    }
#pragma unroll
    for (int k4 = 0; k4 < 32; ++k4) {
        float4 v = x2p[k4];
        int c = k4 * 4;
        v.x = fmaxf(0.f, fmaf(par[c + 0], v.x, par[128 + c + 0]));
        v.y = fmaxf(0.f, fmaf(par[c + 1], v.y, par[128 + c + 1]));
        v.z = fmaxf(0.f, fmaf(par[c + 2], v.z, par[128 + c + 2]));
        v.w = fmaxf(0.f, fmaf(par[c + 3], v.w, par[128 + c + 3]));
        acc = fmaf(v.x, wl[128 + c + 0][o], acc);
        acc = fmaf(v.y, wl[128 + c + 1][o], acc);
        acc = fmaf(v.z, wl[128 + c + 2][o], acc);
        acc = fmaf(v.w, wl[128 + c + 3][o], acc);
    }
    out[(size_t)row * 16 + o] = acc;
}

// ---------------- launch ----------------

extern "C" void kernel_launch(void* const* d_in, const int* in_sizes, int n_in,
                              void* d_out, int out_size, void* d_ws, size_t ws_size,
                              hipStream_t stream) {
    const float* x   = (const float*)d_in[0];
    const int*   ei  = (const int*)d_in[1];
    const float* W1  = (const float*)d_in[2];
    const float* b1  = (const float*)d_in[3];
    const float* g1w = (const float*)d_in[4];
    const float* g1b = (const float*)d_in[5];
    const float* g1a = (const float*)d_in[6];
    const float* W2  = (const float*)d_in[7];
    const float* b2  = (const float*)d_in[8];
    const float* g2w = (const float*)d_in[9];
    const float* g2b = (const float*)d_in[10];
    const float* g2a = (const float*)d_in[11];
    const float* Wh  = (const float*)d_in[12];
    const float* bh  = (const float*)d_in[13];
    const int* srcp = ei;        // edge_index row 0
    const int* dstp = ei + NE;   // edge_index row 1
    float* out = (float*)d_out;

    char* p = (char*)d_ws;
    auto take = [&](size_t bytes) { char* r = p; p += (bytes + 255) & ~(size_t)255; return r; };
    int*   cnt    = (int*)take((size_t)NN * 4);
    int*   offs   = (int*)take((size_t)(NN + 1) * 4);
    int*   cur    = (int*)take((size_t)NN * 4);
    int*   csrc   = (int*)take((size_t)NE * 4);
    float* dinv   = (float*)take((size_t)NN * 4);
    int*   porder = (int*)take((size_t)NN * 4);
    int*   part   = (int*)take(128 * 4);
    int*   hist   = (int*)take(256 * 4);
    int*   hcur   = (int*)take(256 * 4);
    float* stats1 = (float*)take(256 * 4);
    float* stats2 = (float*)take(256 * 4);
    float* par1   = (float*)take(256 * 4);
    float* par2   = (float*)take(256 * 4);
    uint32* bufH  = (uint32*)take((size_t)NN * 128 * 2);  // bf16, chunked
    float* bufA   = (float*)take((size_t)NN * 128 * 4);

    hipMemsetAsync(cnt, 0, (size_t)NN * 4, stream);
    hipMemsetAsync(hist, 0, 256 * 4, stream);
    hipMemsetAsync(stats1, 0, 256 * 4, stream);
    hipMemsetAsync(stats2, 0, 256 * 4, stream);

    count_k<<<(NE + 255) / 256, 256, 0, stream>>>(dstp, cnt);
    scan_partial_k<<<98, 256, 0, stream>>>(cnt, part);
    scan_top_k<<<1, 1, 0, stream>>>(part, 98);
    scan_offsets_k<<<98, 256, 0, stream>>>(cnt, part, offs, cur);
    dinv_k<<<(NN + 255) / 256, 256, 0, stream>>>(cnt, dinv);
    fill_k<<<(NE + 255) / 256, 256, 0, stream>>>(srcp, dstp, cur, csrc);
    hist_k<<<(NN + 255) / 256, 256, 0, stream>>>(cnt, hist);
    hscan_k<<<1, 1, 0, stream>>>(hist, hcur);
    scatter_k<<<(NN + 255) / 256, 256, 0, stream>>>(cnt, hcur, porder);

    const int AGG_GRID = (NN / 32) * 8;   // 3125 tiles x 8 chunks

    // layer 1
    gemm128_k<0><<<(NN + 63) / 64, 256, 0, stream>>>(x, W1, nullptr, dinv, bufH);
    aggregate_k<<<AGG_GRID, 256, 0, stream>>>(bufH, offs, csrc, porder, dinv, b1, bufA, stats1);
    gnparams_k<<<1, 128, 0, stream>>>(stats1, g1w, g1b, g1a, par1);

    // layer 2 (gn1+relu fused into GEMM staging)
    gemm128_k<1><<<(NN + 63) / 64, 256, 0, stream>>>(bufA, W2, par1, dinv, bufH);
    aggregate_k<<<AGG_GRID, 256, 0, stream>>>(bufH, offs, csrc, porder, dinv, b2, bufA, stats2);
    gnparams_k<<<1, 128, 0, stream>>>(stats2, g2w, g2b, g2a, par2);

    // head (gn2+relu fused on load)
    final_k<<<(NN + 15) / 16, 256, 0, stream>>>(x, bufA, par2, Wh, bh, out);
}

// Round 4
// 619.382 us; speedup vs baseline: 2.2234x; 2.2234x over previous
//
#include <hip/hip_runtime.h>

#define NN 100000
#define NE 1600000

typedef unsigned int uint32;
typedef float f32x2 __attribute__((ext_vector_type(2)));

__device__ inline unsigned short f2bf(float f) {
    uint32 u = __float_as_uint(f);
    u += 0x7FFFu + ((u >> 16) & 1u);      // round to nearest even
    return (unsigned short)(u >> 16);
}
__device__ inline float bflo(uint32 v) { return __uint_as_float(v << 16); }
__device__ inline float bfhi(uint32 v) { return __uint_as_float(v & 0xFFFF0000u); }

// ---------------- CSR build ----------------

__global__ void count_k(const int* __restrict__ dst, int* __restrict__ cnt) {
    int e = blockIdx.x * 256 + threadIdx.x;
    if (e < NE) atomicAdd(&cnt[dst[e]], 1);
}

__global__ void scan_partial_k(const int* __restrict__ cnt, int* __restrict__ part) {
    __shared__ int sh[256];
    int t = threadIdx.x;
    int base = blockIdx.x * 1024 + t * 4;
    int s = 0;
#pragma unroll
    for (int j = 0; j < 4; ++j) { int i = base + j; if (i < NN) s += cnt[i]; }
    sh[t] = s;
    __syncthreads();
    for (int d = 128; d > 0; d >>= 1) { if (t < d) sh[t] += sh[t + d]; __syncthreads(); }
    if (t == 0) part[blockIdx.x] = sh[0];
}

__global__ void scan_top_k(int* part, int nb) {
    if (threadIdx.x == 0 && blockIdx.x == 0) {
        int run = 0;
        for (int i = 0; i < nb; ++i) { int v = part[i]; part[i] = run; run += v; }
    }
}

__global__ void scan_offsets_k(const int* __restrict__ cnt, const int* __restrict__ part,
                               int* __restrict__ offs, int* __restrict__ cur) {
    __shared__ int sh[256];
    int t = threadIdx.x;
    int base = blockIdx.x * 1024 + t * 4;
    int v[4]; int s = 0;
#pragma unroll
    for (int j = 0; j < 4; ++j) { int i = base + j; v[j] = (i < NN) ? cnt[i] : 0; s += v[j]; }
    sh[t] = s;
    __syncthreads();
    if (t == 0) {
        int run = 0;
        for (int i = 0; i < 256; ++i) { int tmp = sh[i]; sh[i] = run; run += tmp; }
    }
    __syncthreads();
    int excl = part[blockIdx.x] + sh[t];
#pragma unroll
    for (int j = 0; j < 4; ++j) {
        int i = base + j;
        if (i < NN) { offs[i] = excl; cur[i] = excl; }
        excl += v[j];
    }
    if (blockIdx.x == 0 && t == 0) offs[NN] = NE;
}

__global__ void dinv_k(const int* __restrict__ cnt, float* __restrict__ dinv) {
    int i = blockIdx.x * 256 + threadIdx.x;
    if (i < NN) dinv[i] = rsqrtf((float)(cnt[i] + 1));
}

__global__ void fill_k(const int* __restrict__ src, const int* __restrict__ dst,
                       int* __restrict__ cur, int* __restrict__ csrc) {
    int e = blockIdx.x * 256 + threadIdx.x;
    if (e < NE) {
        int d = dst[e];
        int p = atomicAdd(&cur[d], 1);
        csrc[p] = src[e];
    }
}

// ------ dense GEMM: HS[N,128](bf16) = dinv[row] * act(X[N,128]) @ W --------
// AFF=1: apply per-channel relu(sc*x+sh) (fused GraphNorm+ReLU) while staging.

template <int AFF>
__global__ __launch_bounds__(256) void gemm128_k(const float* __restrict__ X,
                                                 const float* __restrict__ W,
                                                 const float* __restrict__ par,
                                                 const float* __restrict__ dinv,
                                                 unsigned short* __restrict__ HS) {
    __shared__ float xs[64][132];   // +4 pad: breaks power-of-2 bank stride
    int t = threadIdx.x;
    int row0 = blockIdx.x * 64;
    for (int i = t; i < 64 * 32; i += 256) {
        int r = i >> 5, c4 = i & 31;
        int row = row0 + r;
        float4 v = make_float4(0.f, 0.f, 0.f, 0.f);
        if (row < NN) v = ((const float4*)(X + (size_t)row * 128))[c4];
        if (AFF) {
            int c = c4 * 4;
            v.x = fmaxf(0.f, fmaf(par[c + 0], v.x, par[128 + c + 0]));
            v.y = fmaxf(0.f, fmaf(par[c + 1], v.y, par[128 + c + 1]));
            v.z = fmaxf(0.f, fmaf(par[c + 2], v.z, par[128 + c + 2]));
            v.w = fmaxf(0.f, fmaf(par[c + 3], v.w, par[128 + c + 3]));
        }
        *(float4*)&xs[r][c4 * 4] = v;
    }
    __syncthreads();
    int tx = t & 15, ty = t >> 4;      // 16 col-groups x 16 row-groups
    float acc[4][8];
#pragma unroll
    for (int r = 0; r < 4; ++r)
#pragma unroll
        for (int j = 0; j < 8; ++j) acc[r][j] = 0.f;

    for (int k = 0; k < 128; ++k) {
        float4 w0 = *(const float4*)(W + k * 128 + tx * 8);
        float4 w1 = *(const float4*)(W + k * 128 + tx * 8 + 4);
        float xv[4];
#pragma unroll
        for (int r = 0; r < 4; ++r) xv[r] = xs[ty * 4 + r][k];
#pragma unroll
        for (int r = 0; r < 4; ++r) {
            acc[r][0] = fmaf(xv[r], w0.x, acc[r][0]);
            acc[r][1] = fmaf(xv[r], w0.y, acc[r][1]);
            acc[r][2] = fmaf(xv[r], w0.z, acc[r][2]);
            acc[r][3] = fmaf(xv[r], w0.w, acc[r][3]);
            acc[r][4] = fmaf(xv[r], w1.x, acc[r][4]);
            acc[r][5] = fmaf(xv[r], w1.y, acc[r][5]);
            acc[r][6] = fmaf(xv[r], w1.z, acc[r][6]);
            acc[r][7] = fmaf(xv[r], w1.w, acc[r][7]);
        }
    }
#pragma unroll
    for (int r = 0; r < 4; ++r) {
        int row = row0 + ty * 4 + r;
        if (row < NN) {
            float d = dinv[row];
            uint4 o;
            o.x = (uint32)f2bf(d * acc[r][0]) | ((uint32)f2bf(d * acc[r][1]) << 16);
            o.y = (uint32)f2bf(d * acc[r][2]) | ((uint32)f2bf(d * acc[r][3]) << 16);
            o.z = (uint32)f2bf(d * acc[r][4]) | ((uint32)f2bf(d * acc[r][5]) << 16);
            o.w = (uint32)f2bf(d * acc[r][6]) | ((uint32)f2bf(d * acc[r][7]) << 16);
            ((uint4*)(HS + (size_t)row * 128))[tx] = o;
        }
    }
}

// ---------------- edge aggregation (atomic-free, CSR by dst, bf16 gather) ---
// hs rows are pre-scaled by dinv, so:
// out[i,c] = dinv[i]*( sum_e hs[src,c] + hs[i,c] ) + bias[c]
// One wave per node; lane owns channels {2*lane, 2*lane+1} via one uint load.
// 8-deep MLP unroll: 8 independent row-gathers in flight per wave.

__global__ __launch_bounds__(256) void aggregate_k(const uint32* __restrict__ hv,
                                                   const int* __restrict__ offs,
                                                   const int* __restrict__ csrc,
                                                   const float* __restrict__ dinv,
                                                   const float* __restrict__ bias,
                                                   float* __restrict__ out) {
    int t = threadIdx.x;
    int node = blockIdx.x * 4 + (t >> 6);
    if (node >= NN) return;
    int lane = t & 63;
    int beg = offs[node], end = offs[node + 1];
    float di = dinv[node];
    uint32 sv = hv[(size_t)node * 64 + lane];   // self (pre-scaled)
    float a0 = bflo(sv), a1 = bfhi(sv);
    int e = beg;
    for (; e + 7 < end; e += 8) {
        int s0 = csrc[e + 0], s1 = csrc[e + 1], s2 = csrc[e + 2], s3 = csrc[e + 3];
        int s4 = csrc[e + 4], s5 = csrc[e + 5], s6 = csrc[e + 6], s7 = csrc[e + 7];
        uint32 v0 = hv[(size_t)s0 * 64 + lane];
        uint32 v1 = hv[(size_t)s1 * 64 + lane];
        uint32 v2 = hv[(size_t)s2 * 64 + lane];
        uint32 v3 = hv[(size_t)s3 * 64 + lane];
        uint32 v4 = hv[(size_t)s4 * 64 + lane];
        uint32 v5 = hv[(size_t)s5 * 64 + lane];
        uint32 v6 = hv[(size_t)s6 * 64 + lane];
        uint32 v7 = hv[(size_t)s7 * 64 + lane];
        a0 += ((bflo(v0) + bflo(v1)) + (bflo(v2) + bflo(v3)))
            + ((bflo(v4) + bflo(v5)) + (bflo(v6) + bflo(v7)));
        a1 += ((bfhi(v0) + bfhi(v1)) + (bfhi(v2) + bfhi(v3)))
            + ((bfhi(v4) + bfhi(v5)) + (bfhi(v6) + bfhi(v7)));
    }
    for (; e + 3 < end; e += 4) {
        int s0 = csrc[e + 0], s1 = csrc[e + 1], s2 = csrc[e + 2], s3 = csrc[e + 3];
        uint32 v0 = hv[(size_t)s0 * 64 + lane];
        uint32 v1 = hv[(size_t)s1 * 64 + lane];
        uint32 v2 = hv[(size_t)s2 * 64 + lane];
        uint32 v3 = hv[(size_t)s3 * 64 + lane];
        a0 += (bflo(v0) + bflo(v1)) + (bflo(v2) + bflo(v3));
        a1 += (bfhi(v0) + bfhi(v1)) + (bfhi(v2) + bfhi(v3));
    }
    for (; e < end; ++e) {
        int s0 = csrc[e];
        uint32 v0 = hv[(size_t)s0 * 64 + lane];
        a0 += bflo(v0);
        a1 += bfhi(v0);
    }
    float2 bb = ((const float2*)bias)[lane];
    f32x2 o;
    o.x = fmaf(di, a0, bb.x);
    o.y = fmaf(di, a1, bb.y);
    ((f32x2*)out)[(size_t)node * 64 + lane] = o;
}

// ---------------- GraphNorm stats ----------------

__global__ __launch_bounds__(256) void colstats_k(const float* __restrict__ A,
                                                  float* __restrict__ stats) {
    __shared__ float sh[512];
    int t = threadIdx.x;
    int c = t & 127;
    float s = 0.f, q = 0.f;
    for (int r = blockIdx.x * 2 + (t >> 7); r < NN; r += gridDim.x * 2) {
        float v = A[(size_t)r * 128 + c];
        s += v; q = fmaf(v, v, q);
    }
    sh[t] = s; sh[256 + t] = q;
    __syncthreads();
    if (t < 128) {
        atomicAdd(&stats[c], sh[t] + sh[t + 128]);
        atomicAdd(&stats[128 + c], sh[256 + t] + sh[256 + t + 128]);
    }
}

__global__ void gnparams_k(const float* __restrict__ stats, const float* __restrict__ w,
                           const float* __restrict__ b, const float* __restrict__ a,
                           float* __restrict__ par) {
    int c = threadIdx.x;
    if (c < 128) {
        float m = stats[c] * (1.0f / NN);
        float ex2 = stats[128 + c] * (1.0f / NN);
        float ac = a[c];
        // var of (x - a*m): E[x^2] - 2*a*m^2 + a^2*m^2
        float var = ex2 - 2.0f * ac * m * m + ac * ac * m * m;
        float sc = w[c] * rsqrtf(var + 1e-5f);
        par[c] = sc;                       // scale
        par[128 + c] = b[c] - sc * ac * m; // shift
    }
}

// ---------------- head: out = [x, relu(gn2(x2))] @ Wh + bh ----------------

__global__ __launch_bounds__(256) void final_k(const float* __restrict__ x,
                                               const float* __restrict__ x2,
                                               const float* __restrict__ par,
                                               const float* __restrict__ Wh,
                                               const float* __restrict__ bh,
                                               float* __restrict__ out) {
    __shared__ float wl[256][16];
    int t = threadIdx.x;
    for (int i = t; i < 256 * 16; i += 256) wl[i >> 4][i & 15] = Wh[i];
    __syncthreads();
    int row = blockIdx.x * 16 + (t >> 4);
    int o = t & 15;
    if (row >= NN) return;
    const float4* xp = (const float4*)(x + (size_t)row * 128);
    const float4* x2p = (const float4*)(x2 + (size_t)row * 128);
    float acc = bh[o];
#pragma unroll
    for (int k4 = 0; k4 < 32; ++k4) {
        float4 v = xp[k4];
        acc = fmaf(v.x, wl[k4 * 4 + 0][o], acc);
        acc = fmaf(v.y, wl[k4 * 4 + 1][o], acc);
        acc = fmaf(v.z, wl[k4 * 4 + 2][o], acc);
        acc = fmaf(v.w, wl[k4 * 4 + 3][o], acc);
    }
#pragma unroll
    for (int k4 = 0; k4 < 32; ++k4) {
        float4 v = x2p[k4];
        int c = k4 * 4;
        v.x = fmaxf(0.f, fmaf(par[c + 0], v.x, par[128 + c + 0]));
        v.y = fmaxf(0.f, fmaf(par[c + 1], v.y, par[128 + c + 1]));
        v.z = fmaxf(0.f, fmaf(par[c + 2], v.z, par[128 + c + 2]));
        v.w = fmaxf(0.f, fmaf(par[c + 3], v.w, par[128 + c + 3]));
        acc = fmaf(v.x, wl[128 + c + 0][o], acc);
        acc = fmaf(v.y, wl[128 + c + 1][o], acc);
        acc = fmaf(v.z, wl[128 + c + 2][o], acc);
        acc = fmaf(v.w, wl[128 + c + 3][o], acc);
    }
    out[(size_t)row * 16 + o] = acc;
}

// ---------------- launch ----------------

extern "C" void kernel_launch(void* const* d_in, const int* in_sizes, int n_in,
                              void* d_out, int out_size, void* d_ws, size_t ws_size,
                              hipStream_t stream) {
    const float* x   = (const float*)d_in[0];
    const int*   ei  = (const int*)d_in[1];
    const float* W1  = (const float*)d_in[2];
    const float* b1  = (const float*)d_in[3];
    const float* g1w = (const float*)d_in[4];
    const float* g1b = (const float*)d_in[5];
    const float* g1a = (const float*)d_in[6];
    const float* W2  = (const float*)d_in[7];
    const float* b2  = (const float*)d_in[8];
    const float* g2w = (const float*)d_in[9];
    const float* g2b = (const float*)d_in[10];
    const float* g2a = (const float*)d_in[11];
    const float* Wh  = (const float*)d_in[12];
    const float* bh  = (const float*)d_in[13];
    const int* srcp = ei;        // edge_index row 0
    const int* dstp = ei + NE;   // edge_index row 1
    float* out = (float*)d_out;

    char* p = (char*)d_ws;
    auto take = [&](size_t bytes) { char* r = p; p += (bytes + 255) & ~(size_t)255; return r; };
    int*   cnt    = (int*)take((size_t)NN * 4);
    int*   offs   = (int*)take((size_t)(NN + 1) * 4);
    int*   cur    = (int*)take((size_t)NN * 4);
    int*   csrc   = (int*)take((size_t)NE * 4);
    float* dinv   = (float*)take((size_t)NN * 4);
    int*   part   = (int*)take(128 * 4);
    float* stats1 = (float*)take(256 * 4);
    float* stats2 = (float*)take(256 * 4);
    float* par1   = (float*)take(256 * 4);
    float* par2   = (float*)take(256 * 4);
    unsigned short* bufH = (unsigned short*)take((size_t)NN * 128 * 2);  // bf16
    float* bufA   = (float*)take((size_t)NN * 128 * 4);

    hipMemsetAsync(cnt, 0, (size_t)NN * 4, stream);
    hipMemsetAsync(stats1, 0, 256 * 4, stream);
    hipMemsetAsync(stats2, 0, 256 * 4, stream);

    count_k<<<(NE + 255) / 256, 256, 0, stream>>>(dstp, cnt);
    scan_partial_k<<<98, 256, 0, stream>>>(cnt, part);
    scan_top_k<<<1, 1, 0, stream>>>(part, 98);
    scan_offsets_k<<<98, 256, 0, stream>>>(cnt, part, offs, cur);
    dinv_k<<<(NN + 255) / 256, 256, 0, stream>>>(cnt, dinv);
    fill_k<<<(NE + 255) / 256, 256, 0, stream>>>(srcp, dstp, cur, csrc);

    // layer 1: h1 = dinv * (x @ W1) (bf16), agg -> bufA, stats -> par1
    gemm128_k<0><<<(NN + 63) / 64, 256, 0, stream>>>(x, W1, nullptr, dinv, bufH);
    aggregate_k<<<(NN + 3) / 4, 256, 0, stream>>>((const uint32*)bufH, offs, csrc, dinv, b1, bufA);
    colstats_k<<<512, 256, 0, stream>>>(bufA, stats1);
    gnparams_k<<<1, 128, 0, stream>>>(stats1, g1w, g1b, g1a, par1);

    // layer 2: h2 = dinv * (relu(gn1(bufA)) @ W2) (affine fused on load)
    gemm128_k<1><<<(NN + 63) / 64, 256, 0, stream>>>(bufA, W2, par1, dinv, bufH);
    aggregate_k<<<(NN + 3) / 4, 256, 0, stream>>>((const uint32*)bufH, offs, csrc, dinv, b2, bufA);
    colstats_k<<<512, 256, 0, stream>>>(bufA, stats2);
    gnparams_k<<<1, 128, 0, stream>>>(stats2, g2w, g2b, g2a, par2);

    // head: out = [x, relu(gn2(bufA))] @ Wh + bh (gn2 fused on load)
    final_k<<<(NN + 15) / 16, 256, 0, stream>>>(x, bufA, par2, Wh, bh, out);
}

// Round 5
// 551.561 us; speedup vs baseline: 2.4967x; 1.1230x over previous
//
#include <hip/hip_runtime.h>

#define NN 100000
#define NE 1600000

#define COUNT_GRID 6250     // 1.6M edges, 1/thread
#define GEMM1_GRID 3125     // 32-row tiles, 3125*32 = 100000
#define FILL_GRID  6250
#define SCALE_GRID 3125     // 800K threads, 8 uints each

typedef unsigned int uint32;
typedef float f32x2 __attribute__((ext_vector_type(2)));

__device__ inline unsigned short f2bf(float f) {
    uint32 u = __float_as_uint(f);
    u += 0x7FFFu + ((u >> 16) & 1u);      // round to nearest even
    return (unsigned short)(u >> 16);
}
__device__ inline float bflo(uint32 v) { return __uint_as_float(v << 16); }
__device__ inline float bfhi(uint32 v) { return __uint_as_float(v & 0xFFFF0000u); }
__device__ inline uint32 scale2(float d, uint32 v) {
    return (uint32)f2bf(d * bflo(v)) | ((uint32)f2bf(d * bfhi(v)) << 16);
}

// ---------------- GEMM body: HS[N,128](bf16) = [dinv*] act(X) @ W ----------
// AFF: apply relu(sc*x+sh) on load (fused GraphNorm+ReLU). SCALE: dinv prescale.

template <int AFF, int ROWS, int SCALE>
__device__ __forceinline__ void gemm_body(int bid, const float* __restrict__ X,
                                          const float* __restrict__ W,
                                          const float* __restrict__ par,
                                          const float* __restrict__ dinv,
                                          unsigned short* __restrict__ HS) {
    __shared__ float xs[ROWS][132];   // +4 pad: breaks power-of-2 bank stride
    const int RPT = ROWS / 16;        // rows per ty-group
    int t = threadIdx.x;
    int row0 = bid * ROWS;
    for (int i = t; i < ROWS * 32; i += 256) {
        int r = i >> 5, c4 = i & 31;
        int row = row0 + r;
        float4 v = make_float4(0.f, 0.f, 0.f, 0.f);
        if (row < NN) v = ((const float4*)(X + (size_t)row * 128))[c4];
        if (AFF) {
            int c = c4 * 4;
            v.x = fmaxf(0.f, fmaf(par[c + 0], v.x, par[128 + c + 0]));
            v.y = fmaxf(0.f, fmaf(par[c + 1], v.y, par[128 + c + 1]));
            v.z = fmaxf(0.f, fmaf(par[c + 2], v.z, par[128 + c + 2]));
            v.w = fmaxf(0.f, fmaf(par[c + 3], v.w, par[128 + c + 3]));
        }
        *(float4*)&xs[r][c4 * 4] = v;
    }
    __syncthreads();
    int tx = t & 15, ty = t >> 4;      // 16 col-groups x 16 row-groups
    float acc[RPT][8];
#pragma unroll
    for (int r = 0; r < RPT; ++r)
#pragma unroll
        for (int j = 0; j < 8; ++j) acc[r][j] = 0.f;

    for (int k = 0; k < 128; ++k) {
        float4 w0 = *(const float4*)(W + k * 128 + tx * 8);
        float4 w1 = *(const float4*)(W + k * 128 + tx * 8 + 4);
        float xv[RPT];
#pragma unroll
        for (int r = 0; r < RPT; ++r) xv[r] = xs[ty * RPT + r][k];
#pragma unroll
        for (int r = 0; r < RPT; ++r) {
            acc[r][0] = fmaf(xv[r], w0.x, acc[r][0]);
            acc[r][1] = fmaf(xv[r], w0.y, acc[r][1]);
            acc[r][2] = fmaf(xv[r], w0.z, acc[r][2]);
            acc[r][3] = fmaf(xv[r], w0.w, acc[r][3]);
            acc[r][4] = fmaf(xv[r], w1.x, acc[r][4]);
            acc[r][5] = fmaf(xv[r], w1.y, acc[r][5]);
            acc[r][6] = fmaf(xv[r], w1.z, acc[r][6]);
            acc[r][7] = fmaf(xv[r], w1.w, acc[r][7]);
        }
    }
#pragma unroll
    for (int r = 0; r < RPT; ++r) {
        int row = row0 + ty * RPT + r;
        if (row < NN) {
            float d = SCALE ? dinv[row] : 1.0f;
            uint4 o;
            o.x = (uint32)f2bf(d * acc[r][0]) | ((uint32)f2bf(d * acc[r][1]) << 16);
            o.y = (uint32)f2bf(d * acc[r][2]) | ((uint32)f2bf(d * acc[r][3]) << 16);
            o.z = (uint32)f2bf(d * acc[r][4]) | ((uint32)f2bf(d * acc[r][5]) << 16);
            o.w = (uint32)f2bf(d * acc[r][6]) | ((uint32)f2bf(d * acc[r][7]) << 16);
            ((uint4*)(HS + (size_t)row * 128))[tx] = o;
        }
    }
}

template <int AFF, int ROWS, int SCALE>
__global__ __launch_bounds__(256) void gemm_k(const float* __restrict__ X,
                                              const float* __restrict__ W,
                                              const float* __restrict__ par,
                                              const float* __restrict__ dinv,
                                              unsigned short* __restrict__ HS) {
    gemm_body<AFF, ROWS, SCALE>(blockIdx.x, X, W, par, dinv, HS);
}

// ---- fused: edge count+rank (atomic, latency-bound)  ∥  GEMM1 (VALU-bound) -

__global__ __launch_bounds__(256) void gemm1_count_k(const float* __restrict__ X,
                                                     const float* __restrict__ W1,
                                                     unsigned short* __restrict__ HS,
                                                     const int* __restrict__ dst,
                                                     int* __restrict__ cnt,
                                                     int* __restrict__ rank) {
    if (blockIdx.x < COUNT_GRID) {
        int e = blockIdx.x * 256 + threadIdx.x;     // grid exactly covers NE
        int d = dst[e];
        rank[e] = atomicAdd(&cnt[d], 1);
    } else {
        gemm_body<0, 32, 0>(blockIdx.x - COUNT_GRID, X, W1, nullptr, nullptr, HS);
    }
}

// ---------------- scans over cnt -> offs ----------------

__global__ void scan_partial_k(const int* __restrict__ cnt, int* __restrict__ part) {
    __shared__ int sh[256];
    int t = threadIdx.x;
    int base = blockIdx.x * 1024 + t * 4;
    int s = 0;
#pragma unroll
    for (int j = 0; j < 4; ++j) { int i = base + j; if (i < NN) s += cnt[i]; }
    sh[t] = s;
    __syncthreads();
    for (int d = 128; d > 0; d >>= 1) { if (t < d) sh[t] += sh[t + d]; __syncthreads(); }
    if (t == 0) part[blockIdx.x] = sh[0];
}

__global__ void scan_top_k(int* part, int nb) {
    if (threadIdx.x == 0 && blockIdx.x == 0) {
        int run = 0;
        for (int i = 0; i < nb; ++i) { int v = part[i]; part[i] = run; run += v; }
    }
}

__global__ void scan_offsets_k(const int* __restrict__ cnt, const int* __restrict__ part,
                               int* __restrict__ offs) {
    __shared__ int sh[256];
    int t = threadIdx.x;
    int base = blockIdx.x * 1024 + t * 4;
    int v[4]; int s = 0;
#pragma unroll
    for (int j = 0; j < 4; ++j) { int i = base + j; v[j] = (i < NN) ? cnt[i] : 0; s += v[j]; }
    sh[t] = s;
    __syncthreads();
    if (t == 0) {
        int run = 0;
        for (int i = 0; i < 256; ++i) { int tmp = sh[i]; sh[i] = run; run += tmp; }
    }
    __syncthreads();
    int excl = part[blockIdx.x] + sh[t];
#pragma unroll
    for (int j = 0; j < 4; ++j) {
        int i = base + j;
        if (i < NN) offs[i] = excl;
        excl += v[j];
    }
    if (blockIdx.x == 0 && t == 0) offs[NN] = NE;
}

__global__ void dinv_k(const int* __restrict__ cnt, float* __restrict__ dinv) {
    int i = blockIdx.x * 256 + threadIdx.x;
    if (i < NN) dinv[i] = rsqrtf((float)(cnt[i] + 1));
}

// ---- fused: CSR fill (pure scatter, no atomic)  ∥  dinv-prescale of bufH ---

__global__ __launch_bounds__(256) void fill_scale_k(const int* __restrict__ src,
                                                    const int* __restrict__ dst,
                                                    const int* __restrict__ rank,
                                                    const int* __restrict__ offs,
                                                    int* __restrict__ csrc,
                                                    uint32* __restrict__ h,
                                                    const float* __restrict__ dinv) {
    if (blockIdx.x < FILL_GRID) {
        int e = blockIdx.x * 256 + threadIdx.x;     // grid exactly covers NE
        csrc[offs[dst[e]] + rank[e]] = src[e];
    } else {
        int tid = (blockIdx.x - FILL_GRID) * 256 + threadIdx.x;  // 800K, exact
        int row = tid >> 3;
        int u = (tid & 7) * 8;
        float d = dinv[row];
        uint32* p = h + (size_t)row * 64 + u;
        uint4 a = *(uint4*)p;
        uint4 b = *(uint4*)(p + 4);
        a.x = scale2(d, a.x); a.y = scale2(d, a.y);
        a.z = scale2(d, a.z); a.w = scale2(d, a.w);
        b.x = scale2(d, b.x); b.y = scale2(d, b.y);
        b.z = scale2(d, b.z); b.w = scale2(d, b.w);
        *(uint4*)p = a;
        *(uint4*)(p + 4) = b;
    }
}

// ---------------- edge aggregation (atomic-free, CSR by dst, bf16 gather) ---
// hs rows pre-scaled by dinv:
// out[i,c] = dinv[i]*( sum_e hs[src,c] + hs[i,c] ) + bias[c]
// One wave per node; lane owns channels {2*lane, 2*lane+1} via one uint load.
// 8-deep MLP unroll: 8 independent row-gathers in flight per wave.

__global__ __launch_bounds__(256) void aggregate_k(const uint32* __restrict__ hv,
                                                   const int* __restrict__ offs,
                                                   const int* __restrict__ csrc,
                                                   const float* __restrict__ dinv,
                                                   const float* __restrict__ bias,
                                                   float* __restrict__ out) {
    int t = threadIdx.x;
    int node = blockIdx.x * 4 + (t >> 6);
    if (node >= NN) return;
    int lane = t & 63;
    int beg = offs[node], end = offs[node + 1];
    float di = dinv[node];
    uint32 sv = hv[(size_t)node * 64 + lane];   // self (pre-scaled)
    float a0 = bflo(sv), a1 = bfhi(sv);
    int e = beg;
    for (; e + 7 < end; e += 8) {
        int s0 = csrc[e + 0], s1 = csrc[e + 1], s2 = csrc[e + 2], s3 = csrc[e + 3];
        int s4 = csrc[e + 4], s5 = csrc[e + 5], s6 = csrc[e + 6], s7 = csrc[e + 7];
        uint32 v0 = hv[(size_t)s0 * 64 + lane];
        uint32 v1 = hv[(size_t)s1 * 64 + lane];
        uint32 v2 = hv[(size_t)s2 * 64 + lane];
        uint32 v3 = hv[(size_t)s3 * 64 + lane];
        uint32 v4 = hv[(size_t)s4 * 64 + lane];
        uint32 v5 = hv[(size_t)s5 * 64 + lane];
        uint32 v6 = hv[(size_t)s6 * 64 + lane];
        uint32 v7 = hv[(size_t)s7 * 64 + lane];
        a0 += ((bflo(v0) + bflo(v1)) + (bflo(v2) + bflo(v3)))
            + ((bflo(v4) + bflo(v5)) + (bflo(v6) + bflo(v7)));
        a1 += ((bfhi(v0) + bfhi(v1)) + (bfhi(v2) + bfhi(v3)))
            + ((bfhi(v4) + bfhi(v5)) + (bfhi(v6) + bfhi(v7)));
    }
    for (; e + 3 < end; e += 4) {
        int s0 = csrc[e + 0], s1 = csrc[e + 1], s2 = csrc[e + 2], s3 = csrc[e + 3];
        uint32 v0 = hv[(size_t)s0 * 64 + lane];
        uint32 v1 = hv[(size_t)s1 * 64 + lane];
        uint32 v2 = hv[(size_t)s2 * 64 + lane];
        uint32 v3 = hv[(size_t)s3 * 64 + lane];
        a0 += (bflo(v0) + bflo(v1)) + (bflo(v2) + bflo(v3));
        a1 += (bfhi(v0) + bfhi(v1)) + (bfhi(v2) + bfhi(v3));
    }
    for (; e < end; ++e) {
        int s0 = csrc[e];
        uint32 v0 = hv[(size_t)s0 * 64 + lane];
        a0 += bflo(v0);
        a1 += bfhi(v0);
    }
    float2 bb = ((const float2*)bias)[lane];
    f32x2 o;
    o.x = fmaf(di, a0, bb.x);
    o.y = fmaf(di, a1, bb.y);
    ((f32x2*)out)[(size_t)node * 64 + lane] = o;
}

// ---------------- GraphNorm stats ----------------

__global__ __launch_bounds__(256) void colstats_k(const float* __restrict__ A,
                                                  float* __restrict__ stats) {
    __shared__ float sh[512];
    int t = threadIdx.x;
    int c = t & 127;
    float s = 0.f, q = 0.f;
    for (int r = blockIdx.x * 2 + (t >> 7); r < NN; r += gridDim.x * 2) {
        float v = A[(size_t)r * 128 + c];
        s += v; q = fmaf(v, v, q);
    }
    sh[t] = s; sh[256 + t] = q;
    __syncthreads();
    if (t < 128) {
        atomicAdd(&stats[c], sh[t] + sh[t + 128]);
        atomicAdd(&stats[128 + c], sh[256 + t] + sh[256 + t + 128]);
    }
}

__global__ void gnparams_k(const float* __restrict__ stats, const float* __restrict__ w,
                           const float* __restrict__ b, const float* __restrict__ a,
                           float* __restrict__ par) {
    int c = threadIdx.x;
    if (c < 128) {
        float m = stats[c] * (1.0f / NN);
        float ex2 = stats[128 + c] * (1.0f / NN);
        float ac = a[c];
        // var of (x - a*m): E[x^2] - 2*a*m^2 + a^2*m^2
        float var = ex2 - 2.0f * ac * m * m + ac * ac * m * m;
        float sc = w[c] * rsqrtf(var + 1e-5f);
        par[c] = sc;                       // scale
        par[128 + c] = b[c] - sc * ac * m; // shift
    }
}

// ---------------- head: out = [x, relu(gn2(x2))] @ Wh + bh ----------------

__global__ __launch_bounds__(256) void final_k(const float* __restrict__ x,
                                               const float* __restrict__ x2,
                                               const float* __restrict__ par,
                                               const float* __restrict__ Wh,
                                               const float* __restrict__ bh,
                                               float* __restrict__ out) {
    __shared__ float wl[256][16];
    int t = threadIdx.x;
    for (int i = t; i < 256 * 16; i += 256) wl[i >> 4][i & 15] = Wh[i];
    __syncthreads();
    int row = blockIdx.x * 16 + (t >> 4);
    int o = t & 15;
    if (row >= NN) return;
    const float4* xp = (const float4*)(x + (size_t)row * 128);
    const float4* x2p = (const float4*)(x2 + (size_t)row * 128);
    float acc = bh[o];
#pragma unroll
    for (int k4 = 0; k4 < 32; ++k4) {
        float4 v = xp[k4];
        acc = fmaf(v.x, wl[k4 * 4 + 0][o], acc);
        acc = fmaf(v.y, wl[k4 * 4 + 1][o], acc);
        acc = fmaf(v.z, wl[k4 * 4 + 2][o], acc);
        acc = fmaf(v.w, wl[k4 * 4 + 3][o], acc);
    }
#pragma unroll
    for (int k4 = 0; k4 < 32; ++k4) {
        float4 v = x2p[k4];
        int c = k4 * 4;
        v.x = fmaxf(0.f, fmaf(par[c + 0], v.x, par[128 + c + 0]));
        v.y = fmaxf(0.f, fmaf(par[c + 1], v.y, par[128 + c + 1]));
        v.z = fmaxf(0.f, fmaf(par[c + 2], v.z, par[128 + c + 2]));
        v.w = fmaxf(0.f, fmaf(par[c + 3], v.w, par[128 + c + 3]));
        acc = fmaf(v.x, wl[128 + c + 0][o], acc);
        acc = fmaf(v.y, wl[128 + c + 1][o], acc);
        acc = fmaf(v.z, wl[128 + c + 2][o], acc);
        acc = fmaf(v.w, wl[128 + c + 3][o], acc);
    }
    out[(size_t)row * 16 + o] = acc;
}

// ---------------- launch ----------------

extern "C" void kernel_launch(void* const* d_in, const int* in_sizes, int n_in,
                              void* d_out, int out_size, void* d_ws, size_t ws_size,
                              hipStream_t stream) {
    const float* x   = (const float*)d_in[0];
    const int*   ei  = (const int*)d_in[1];
    const float* W1  = (const float*)d_in[2];
    const float* b1  = (const float*)d_in[3];
    const float* g1w = (const float*)d_in[4];
    const float* g1b = (const float*)d_in[5];
    const float* g1a = (const float*)d_in[6];
    const float* W2  = (const float*)d_in[7];
    const float* b2  = (const float*)d_in[8];
    const float* g2w = (const float*)d_in[9];
    const float* g2b = (const float*)d_in[10];
    const float* g2a = (const float*)d_in[11];
    const float* Wh  = (const float*)d_in[12];
    const float* bh  = (const float*)d_in[13];
    const int* srcp = ei;        // edge_index row 0
    const int* dstp = ei + NE;   // edge_index row 1
    float* out = (float*)d_out;

    char* p = (char*)d_ws;
    auto take = [&](size_t bytes) { char* r = p; p += (bytes + 255) & ~(size_t)255; return r; };
    int*   cnt    = (int*)take((size_t)NN * 4);
    int*   offs   = (int*)take((size_t)(NN + 1) * 4);
    int*   rank   = (int*)take((size_t)NE * 4);
    int*   csrc   = (int*)take((size_t)NE * 4);
    float* dinv   = (float*)take((size_t)NN * 4);
    int*   part   = (int*)take(128 * 4);
    float* stats1 = (float*)take(256 * 4);
    float* stats2 = (float*)take(256 * 4);
    float* par1   = (float*)take(256 * 4);
    float* par2   = (float*)take(256 * 4);
    unsigned short* bufH = (unsigned short*)take((size_t)NN * 128 * 2);  // bf16
    float* bufA   = (float*)take((size_t)NN * 128 * 4);

    hipMemsetAsync(cnt, 0, (size_t)NN * 4, stream);
    hipMemsetAsync(stats1, 0, 256 * 4, stream);
    hipMemsetAsync(stats2, 0, 256 * 4, stream);

    // phase 1: count(+rank) ∥ gemm1 (unscaled h1)
    gemm1_count_k<<<COUNT_GRID + GEMM1_GRID, 256, 0, stream>>>(
        x, W1, bufH, dstp, cnt, rank);

    // phase 2: scans + dinv (tiny)
    scan_partial_k<<<98, 256, 0, stream>>>(cnt, part);
    scan_top_k<<<1, 1, 0, stream>>>(part, 98);
    scan_offsets_k<<<98, 256, 0, stream>>>(cnt, part, offs);
    dinv_k<<<(NN + 255) / 256, 256, 0, stream>>>(cnt, dinv);

    // phase 3: CSR fill (no atomics) ∥ dinv-prescale of h1
    fill_scale_k<<<FILL_GRID + SCALE_GRID, 256, 0, stream>>>(
        srcp, dstp, rank, offs, csrc, (uint32*)bufH, dinv);

    // layer 1 aggregate + gn stats
    aggregate_k<<<(NN + 3) / 4, 256, 0, stream>>>((const uint32*)bufH, offs, csrc, dinv, b1, bufA);
    colstats_k<<<512, 256, 0, stream>>>(bufA, stats1);
    gnparams_k<<<1, 128, 0, stream>>>(stats1, g1w, g1b, g1a, par1);

    // layer 2: h2 = dinv * (relu(gn1(bufA)) @ W2), aggregate, stats
    gemm_k<1, 64, 1><<<(NN + 63) / 64, 256, 0, stream>>>(bufA, W2, par1, dinv, bufH);
    aggregate_k<<<(NN + 3) / 4, 256, 0, stream>>>((const uint32*)bufH, offs, csrc, dinv, b2, bufA);
    colstats_k<<<512, 256, 0, stream>>>(bufA, stats2);
    gnparams_k<<<1, 128, 0, stream>>>(stats2, g2w, g2b, g2a, par2);

    // head: out = [x, relu(gn2(bufA))] @ Wh + bh (gn2 fused on load)
    final_k<<<(NN + 15) / 16, 256, 0, stream>>>(x, bufA, par2, Wh, bh, out);
}

// Round 6
// 495.304 us; speedup vs baseline: 2.7803x; 1.1136x over previous
//
#include <hip/hip_runtime.h>

#define NN 100000
#define NE 1600000

#define EBLK 4096
#define NBLK 391            // ceil(NE/EBLK)
#define NBUCK 196           // ceil(NN/512), bucket = dst>>9

typedef unsigned int uint32;
typedef float f32x2 __attribute__((ext_vector_type(2)));

__device__ inline unsigned short f2bf(float f) {
    uint32 u = __float_as_uint(f);
    u += 0x7FFFu + ((u >> 16) & 1u);      // round to nearest even
    return (unsigned short)(u >> 16);
}
__device__ inline float bflo(uint32 v) { return __uint_as_float(v << 16); }
__device__ inline float bfhi(uint32 v) { return __uint_as_float(v & 0xFFFF0000u); }

__device__ inline int wave_incl_scan(int v) {   // 64-lane inclusive scan
#pragma unroll
    for (int d = 1; d < 64; d <<= 1) {
        int u = __shfl_up(v, d, 64);
        if ((threadIdx.x & 63) >= (unsigned)d) v += u;
    }
    return v;
}

// ---------------- CSR build, atomic-free (bucketed) ----------------
// P1: per-block LDS histogram of dst>>9.

__global__ __launch_bounds__(256) void p1_hist_k(const int* __restrict__ dst,
                                                 int* __restrict__ histT) {
    __shared__ int h[256];
    int t = threadIdx.x;
    h[t] = 0;
    __syncthreads();
    int e0 = blockIdx.x * EBLK;
#pragma unroll
    for (int i = 0; i < EBLK / 256; ++i) {
        int e = e0 + i * 256 + t;
        if (e < NE) atomicAdd(&h[dst[e] >> 9], 1);
    }
    __syncthreads();
    histT[t * NBLK + blockIdx.x] = h[t];   // transposed: P2 reads row/thread
}

// P2: bucket totals -> bucket_base (excl scan); per-(block,bucket) offsets.

__global__ __launch_bounds__(256) void p2_scan_k(const int* __restrict__ histT,
                                                 int* __restrict__ blockoff,
                                                 int* __restrict__ bucket_base,
                                                 int* __restrict__ offs) {
    __shared__ int wsum[4];
    int t = threadIdx.x;
    const int* row = histT + t * NBLK;
    int s = 0;
#pragma unroll 4
    for (int blk = 0; blk < NBLK; ++blk) s += row[blk];
    int incl = wave_incl_scan(s);
    if ((t & 63) == 63) wsum[t >> 6] = incl;
    __syncthreads();
    int add = 0;
    for (int w = 0; w < (t >> 6); ++w) add += wsum[w];
    int excl = incl - s + add;
    bucket_base[t] = excl;
    if (t == 255) bucket_base[256] = excl + s;   // == NE
    int run = excl;
    for (int blk = 0; blk < NBLK; ++blk) {
        blockoff[blk * 256 + t] = run;
        run += row[blk];
    }
    if (t == 0) offs[NN] = NE;
}

// P3: scatter packed (dlocal<<17 | src) into bucket-contiguous ebuf.

__global__ __launch_bounds__(256) void p3_scatter_k(const int* __restrict__ src,
                                                    const int* __restrict__ dst,
                                                    const int* __restrict__ blockoff,
                                                    uint32* __restrict__ ebuf) {
    __shared__ int cur[256];
    int t = threadIdx.x;
    cur[t] = blockoff[blockIdx.x * 256 + t];
    __syncthreads();
    int e0 = blockIdx.x * EBLK;
#pragma unroll
    for (int i = 0; i < EBLK / 256; ++i) {
        int e = e0 + i * 256 + t;
        if (e < NE) {
            int d = dst[e];
            int pos = atomicAdd(&cur[d >> 9], 1);      // LDS atomic
            ebuf[pos] = ((uint32)(d & 511) << 17) | (uint32)src[e];
        }
    }
}

// P4: per-bucket (512 nodes) local count/scan -> offs, dinv, csrc.

__global__ __launch_bounds__(256) void p4_csr_k(const uint32* __restrict__ ebuf,
                                                const int* __restrict__ bucket_base,
                                                int* __restrict__ offs,
                                                float* __restrict__ dinv,
                                                int* __restrict__ csrc) {
    __shared__ int cntL[512];
    __shared__ int offL[512];
    __shared__ int wsum[4];
    int t = threadIdx.x;
    int bbase = bucket_base[blockIdx.x];
    int bend  = bucket_base[blockIdx.x + 1];
    cntL[t] = 0; cntL[t + 256] = 0;
    __syncthreads();
    for (int e = bbase + t; e < bend; e += 256)
        atomicAdd(&cntL[ebuf[e] >> 17], 1);
    __syncthreads();
    int c0 = cntL[2 * t], c1 = cntL[2 * t + 1];
    int ps = c0 + c1;
    int incl = wave_incl_scan(ps);
    if ((t & 63) == 63) wsum[t >> 6] = incl;
    __syncthreads();
    int add = 0;
    for (int w = 0; w < (t >> 6); ++w) add += wsum[w];
    int excl = incl - ps + add;
    offL[2 * t] = excl;
    offL[2 * t + 1] = excl + c0;
    int n0 = blockIdx.x * 512;
#pragma unroll
    for (int j = 0; j < 2; ++j) {
        int dl = 2 * t + j;
        int node = n0 + dl;
        if (node < NN) {
            offs[node] = bbase + offL[dl];
            dinv[node] = rsqrtf((float)(cntL[dl] + 1));
        }
    }
    __syncthreads();
    cntL[2 * t] = offL[2 * t];          // reuse as cursors
    cntL[2 * t + 1] = offL[2 * t + 1];
    __syncthreads();
    for (int e = bbase + t; e < bend; e += 256) {
        uint32 v = ebuf[e];
        int pos = atomicAdd(&cntL[v >> 17], 1);   // LDS atomic
        csrc[bbase + pos] = (int)(v & 0x1FFFFu);
    }
}

// ---------------- GEMM: HS[N,128](bf16) = [dinv*] act(X) @ W ----------------
// AFF: relu(sc*x+sh) on load (fused GraphNorm+ReLU). SCALE: dinv prescale.

template <int AFF, int ROWS, int SCALE>
__global__ __launch_bounds__(256) void gemm_k(const float* __restrict__ X,
                                              const float* __restrict__ W,
                                              const float* __restrict__ par,
                                              const float* __restrict__ dinv,
                                              unsigned short* __restrict__ HS) {
    __shared__ float xs[ROWS][132];   // +4 pad: breaks power-of-2 bank stride
    const int RPT = ROWS / 16;        // rows per ty-group
    int t = threadIdx.x;
    int row0 = blockIdx.x * ROWS;
    for (int i = t; i < ROWS * 32; i += 256) {
        int r = i >> 5, c4 = i & 31;
        int row = row0 + r;
        float4 v = make_float4(0.f, 0.f, 0.f, 0.f);
        if (row < NN) v = ((const float4*)(X + (size_t)row * 128))[c4];
        if (AFF) {
            int c = c4 * 4;
            v.x = fmaxf(0.f, fmaf(par[c + 0], v.x, par[128 + c + 0]));
            v.y = fmaxf(0.f, fmaf(par[c + 1], v.y, par[128 + c + 1]));
            v.z = fmaxf(0.f, fmaf(par[c + 2], v.z, par[128 + c + 2]));
            v.w = fmaxf(0.f, fmaf(par[c + 3], v.w, par[128 + c + 3]));
        }
        *(float4*)&xs[r][c4 * 4] = v;
    }
    __syncthreads();
    int tx = t & 15, ty = t >> 4;      // 16 col-groups x 16 row-groups
    float acc[RPT][8];
#pragma unroll
    for (int r = 0; r < RPT; ++r)
#pragma unroll
        for (int j = 0; j < 8; ++j) acc[r][j] = 0.f;

    for (int k = 0; k < 128; ++k) {
        float4 w0 = *(const float4*)(W + k * 128 + tx * 8);
        float4 w1 = *(const float4*)(W + k * 128 + tx * 8 + 4);
        float xv[RPT];
#pragma unroll
        for (int r = 0; r < RPT; ++r) xv[r] = xs[ty * RPT + r][k];
#pragma unroll
        for (int r = 0; r < RPT; ++r) {
            acc[r][0] = fmaf(xv[r], w0.x, acc[r][0]);
            acc[r][1] = fmaf(xv[r], w0.y, acc[r][1]);
            acc[r][2] = fmaf(xv[r], w0.z, acc[r][2]);
            acc[r][3] = fmaf(xv[r], w0.w, acc[r][3]);
            acc[r][4] = fmaf(xv[r], w1.x, acc[r][4]);
            acc[r][5] = fmaf(xv[r], w1.y, acc[r][5]);
            acc[r][6] = fmaf(xv[r], w1.z, acc[r][6]);
            acc[r][7] = fmaf(xv[r], w1.w, acc[r][7]);
        }
    }
#pragma unroll
    for (int r = 0; r < RPT; ++r) {
        int row = row0 + ty * RPT + r;
        if (row < NN) {
            float d = SCALE ? dinv[row] : 1.0f;
            uint4 o;
            o.x = (uint32)f2bf(d * acc[r][0]) | ((uint32)f2bf(d * acc[r][1]) << 16);
            o.y = (uint32)f2bf(d * acc[r][2]) | ((uint32)f2bf(d * acc[r][3]) << 16);
            o.z = (uint32)f2bf(d * acc[r][4]) | ((uint32)f2bf(d * acc[r][5]) << 16);
            o.w = (uint32)f2bf(d * acc[r][6]) | ((uint32)f2bf(d * acc[r][7]) << 16);
            ((uint4*)(HS + (size_t)row * 128))[tx] = o;
        }
    }
}

// ---------------- edge aggregation (atomic-free, CSR by dst, bf16 gather) ---
// hs rows pre-scaled by dinv:
// out[i,c] = dinv[i]*( sum_e hs[src,c] + hs[i,c] ) + bias[c]
// One wave per node; lane owns channels {2*lane, 2*lane+1} via one uint load.
// 8-deep MLP unroll: 8 independent row-gathers in flight per wave.

__global__ __launch_bounds__(256) void aggregate_k(const uint32* __restrict__ hv,
                                                   const int* __restrict__ offs,
                                                   const int* __restrict__ csrc,
                                                   const float* __restrict__ dinv,
                                                   const float* __restrict__ bias,
                                                   float* __restrict__ out) {
    int t = threadIdx.x;
    int node = blockIdx.x * 4 + (t >> 6);
    if (node >= NN) return;
    int lane = t & 63;
    int beg = offs[node], end = offs[node + 1];
    float di = dinv[node];
    uint32 sv = hv[(size_t)node * 64 + lane];   // self (pre-scaled)
    float a0 = bflo(sv), a1 = bfhi(sv);
    int e = beg;
    for (; e + 7 < end; e += 8) {
        int s0 = csrc[e + 0], s1 = csrc[e + 1], s2 = csrc[e + 2], s3 = csrc[e + 3];
        int s4 = csrc[e + 4], s5 = csrc[e + 5], s6 = csrc[e + 6], s7 = csrc[e + 7];
        uint32 v0 = hv[(size_t)s0 * 64 + lane];
        uint32 v1 = hv[(size_t)s1 * 64 + lane];
        uint32 v2 = hv[(size_t)s2 * 64 + lane];
        uint32 v3 = hv[(size_t)s3 * 64 + lane];
        uint32 v4 = hv[(size_t)s4 * 64 + lane];
        uint32 v5 = hv[(size_t)s5 * 64 + lane];
        uint32 v6 = hv[(size_t)s6 * 64 + lane];
        uint32 v7 = hv[(size_t)s7 * 64 + lane];
        a0 += ((bflo(v0) + bflo(v1)) + (bflo(v2) + bflo(v3)))
            + ((bflo(v4) + bflo(v5)) + (bflo(v6) + bflo(v7)));
        a1 += ((bfhi(v0) + bfhi(v1)) + (bfhi(v2) + bfhi(v3)))
            + ((bfhi(v4) + bfhi(v5)) + (bfhi(v6) + bfhi(v7)));
    }
    for (; e + 3 < end; e += 4) {
        int s0 = csrc[e + 0], s1 = csrc[e + 1], s2 = csrc[e + 2], s3 = csrc[e + 3];
        uint32 v0 = hv[(size_t)s0 * 64 + lane];
        uint32 v1 = hv[(size_t)s1 * 64 + lane];
        uint32 v2 = hv[(size_t)s2 * 64 + lane];
        uint32 v3 = hv[(size_t)s3 * 64 + lane];
        a0 += (bflo(v0) + bflo(v1)) + (bflo(v2) + bflo(v3));
        a1 += (bfhi(v0) + bfhi(v1)) + (bfhi(v2) + bfhi(v3));
    }
    for (; e < end; ++e) {
        int s0 = csrc[e];
        uint32 v0 = hv[(size_t)s0 * 64 + lane];
        a0 += bflo(v0);
        a1 += bfhi(v0);
    }
    float2 bb = ((const float2*)bias)[lane];
    f32x2 o;
    o.x = fmaf(di, a0, bb.x);
    o.y = fmaf(di, a1, bb.y);
    ((f32x2*)out)[(size_t)node * 64 + lane] = o;
}

// ---------------- GraphNorm stats ----------------

__global__ __launch_bounds__(256) void colstats_k(const float* __restrict__ A,
                                                  float* __restrict__ stats) {
    __shared__ float sh[512];
    int t = threadIdx.x;
    int c = t & 127;
    float s = 0.f, q = 0.f;
    for (int r = blockIdx.x * 2 + (t >> 7); r < NN; r += gridDim.x * 2) {
        float v = A[(size_t)r * 128 + c];
        s += v; q = fmaf(v, v, q);
    }
    sh[t] = s; sh[256 + t] = q;
    __syncthreads();
    if (t < 128) {
        atomicAdd(&stats[c], sh[t] + sh[t + 128]);
        atomicAdd(&stats[128 + c], sh[256 + t] + sh[256 + t + 128]);
    }
}

__global__ void gnparams_k(const float* __restrict__ stats, const float* __restrict__ w,
                           const float* __restrict__ b, const float* __restrict__ a,
                           float* __restrict__ par) {
    int c = threadIdx.x;
    if (c < 128) {
        float m = stats[c] * (1.0f / NN);
        float ex2 = stats[128 + c] * (1.0f / NN);
        float ac = a[c];
        // var of (x - a*m): E[x^2] - 2*a*m^2 + a^2*m^2
        float var = ex2 - 2.0f * ac * m * m + ac * ac * m * m;
        float sc = w[c] * rsqrtf(var + 1e-5f);
        par[c] = sc;                       // scale
        par[128 + c] = b[c] - sc * ac * m; // shift
    }
}

// ---------------- head: out = [x, relu(gn2(x2))] @ Wh + bh ----------------

__global__ __launch_bounds__(256) void final_k(const float* __restrict__ x,
                                               const float* __restrict__ x2,
                                               const float* __restrict__ par,
                                               const float* __restrict__ Wh,
                                               const float* __restrict__ bh,
                                               float* __restrict__ out) {
    __shared__ float wl[256][16];
    int t = threadIdx.x;
    for (int i = t; i < 256 * 16; i += 256) wl[i >> 4][i & 15] = Wh[i];
    __syncthreads();
    int row = blockIdx.x * 16 + (t >> 4);
    int o = t & 15;
    if (row >= NN) return;
    const float4* xp = (const float4*)(x + (size_t)row * 128);
    const float4* x2p = (const float4*)(x2 + (size_t)row * 128);
    float acc = bh[o];
#pragma unroll
    for (int k4 = 0; k4 < 32; ++k4) {
        float4 v = xp[k4];
        acc = fmaf(v.x, wl[k4 * 4 + 0][o], acc);
        acc = fmaf(v.y, wl[k4 * 4 + 1][o], acc);
        acc = fmaf(v.z, wl[k4 * 4 + 2][o], acc);
        acc = fmaf(v.w, wl[k4 * 4 + 3][o], acc);
    }
#pragma unroll
    for (int k4 = 0; k4 < 32; ++k4) {
        float4 v = x2p[k4];
        int c = k4 * 4;
        v.x = fmaxf(0.f, fmaf(par[c + 0], v.x, par[128 + c + 0]));
        v.y = fmaxf(0.f, fmaf(par[c + 1], v.y, par[128 + c + 1]));
        v.z = fmaxf(0.f, fmaf(par[c + 2], v.z, par[128 + c + 2]));
        v.w = fmaxf(0.f, fmaf(par[c + 3], v.w, par[128 + c + 3]));
        acc = fmaf(v.x, wl[128 + c + 0][o], acc);
        acc = fmaf(v.y, wl[128 + c + 1][o], acc);
        acc = fmaf(v.z, wl[128 + c + 2][o], acc);
        acc = fmaf(v.w, wl[128 + c + 3][o], acc);
    }
    out[(size_t)row * 16 + o] = acc;
}

// ---------------- launch ----------------

extern "C" void kernel_launch(void* const* d_in, const int* in_sizes, int n_in,
                              void* d_out, int out_size, void* d_ws, size_t ws_size,
                              hipStream_t stream) {
    const float* x   = (const float*)d_in[0];
    const int*   ei  = (const int*)d_in[1];
    const float* W1  = (const float*)d_in[2];
    const float* b1  = (const float*)d_in[3];
    const float* g1w = (const float*)d_in[4];
    const float* g1b = (const float*)d_in[5];
    const float* g1a = (const float*)d_in[6];
    const float* W2  = (const float*)d_in[7];
    const float* b2  = (const float*)d_in[8];
    const float* g2w = (const float*)d_in[9];
    const float* g2b = (const float*)d_in[10];
    const float* g2a = (const float*)d_in[11];
    const float* Wh  = (const float*)d_in[12];
    const float* bh  = (const float*)d_in[13];
    const int* srcp = ei;        // edge_index row 0
    const int* dstp = ei + NE;   // edge_index row 1
    float* out = (float*)d_out;

    char* p = (char*)d_ws;
    auto take = [&](size_t bytes) { char* r = p; p += (bytes + 255) & ~(size_t)255; return r; };
    int*   histT  = (int*)take((size_t)256 * NBLK * 4);
    int*   blockoff = (int*)take((size_t)NBLK * 256 * 4);
    int*   bucket_base = (int*)take(257 * 4);
    uint32* ebuf  = (uint32*)take((size_t)NE * 4);
    int*   offs   = (int*)take((size_t)(NN + 1) * 4);
    int*   csrc   = (int*)take((size_t)NE * 4);
    float* dinv   = (float*)take((size_t)NN * 4);
    float* stats1 = (float*)take(256 * 4);
    float* stats2 = (float*)take(256 * 4);
    float* par1   = (float*)take(256 * 4);
    float* par2   = (float*)take(256 * 4);
    unsigned short* bufH = (unsigned short*)take((size_t)NN * 128 * 2);  // bf16
    float* bufA   = (float*)take((size_t)NN * 128 * 4);

    hipMemsetAsync(stats1, 0, 256 * 4, stream);
    hipMemsetAsync(stats2, 0, 256 * 4, stream);

    // CSR build (atomic-free, streaming)
    p1_hist_k<<<NBLK, 256, 0, stream>>>(dstp, histT);
    p2_scan_k<<<1, 256, 0, stream>>>(histT, blockoff, bucket_base, offs);
    p3_scatter_k<<<NBLK, 256, 0, stream>>>(srcp, dstp, blockoff, ebuf);
    p4_csr_k<<<NBUCK, 256, 0, stream>>>(ebuf, bucket_base, offs, dinv, csrc);

    // layer 1: h1 = dinv * (x @ W1) (bf16), aggregate, stats
    gemm_k<0, 64, 1><<<(NN + 63) / 64, 256, 0, stream>>>(x, W1, nullptr, dinv, bufH);
    aggregate_k<<<(NN + 3) / 4, 256, 0, stream>>>((const uint32*)bufH, offs, csrc, dinv, b1, bufA);
    colstats_k<<<512, 256, 0, stream>>>(bufA, stats1);
    gnparams_k<<<1, 128, 0, stream>>>(stats1, g1w, g1b, g1a, par1);

    // layer 2: h2 = dinv * (relu(gn1(bufA)) @ W2), aggregate, stats
    gemm_k<1, 64, 1><<<(NN + 63) / 64, 256, 0, stream>>>(bufA, W2, par1, dinv, bufH);
    aggregate_k<<<(NN + 3) / 4, 256, 0, stream>>>((const uint32*)bufH, offs, csrc, dinv, b2, bufA);
    colstats_k<<<512, 256, 0, stream>>>(bufA, stats2);
    gnparams_k<<<1, 128, 0, stream>>>(stats2, g2w, g2b, g2a, par2);

    // head: out = [x, relu(gn2(bufA))] @ Wh + bh (gn2 fused on load)
    final_k<<<(NN + 15) / 16, 256, 0, stream>>>(x, bufA, par2, Wh, bh, out);
}

// Round 7
// 483.850 us; speedup vs baseline: 2.8461x; 1.0237x over previous
//
#include <hip/hip_runtime.h>

#define NN 100000
#define NE 1600000

#define EBLK 4096
#define NBLK 391            // ceil(NE/EBLK)
#define NBUCK 196           // ceil(NN/512), bucket = dst>>9

typedef unsigned int uint32;

__device__ inline unsigned short f2bf(float f) {
    uint32 u = __float_as_uint(f);
    u += 0x7FFFu + ((u >> 16) & 1u);      // round to nearest even
    return (unsigned short)(u >> 16);
}
__device__ inline float bflo(uint32 v) { return __uint_as_float(v << 16); }
__device__ inline float bfhi(uint32 v) { return __uint_as_float(v & 0xFFFF0000u); }

__device__ inline int wave_incl_scan(int v) {   // 64-lane inclusive scan
#pragma unroll
    for (int d = 1; d < 64; d <<= 1) {
        int u = __shfl_up(v, d, 64);
        if ((threadIdx.x & 63) >= (unsigned)d) v += u;
    }
    return v;
}

// ---------------- CSR build, atomic-free (bucketed) ----------------

__global__ __launch_bounds__(256) void p1_hist_k(const int* __restrict__ dst,
                                                 int* __restrict__ histT) {
    __shared__ int h[256];
    int t = threadIdx.x;
    h[t] = 0;
    __syncthreads();
    int e0 = blockIdx.x * EBLK;
#pragma unroll
    for (int i = 0; i < EBLK / 256; ++i) {
        int e = e0 + i * 256 + t;
        if (e < NE) atomicAdd(&h[dst[e] >> 9], 1);
    }
    __syncthreads();
    histT[t * NBLK + blockIdx.x] = h[t];   // transposed: P2 reads row/thread
}

__global__ __launch_bounds__(256) void p2_scan_k(const int* __restrict__ histT,
                                                 int* __restrict__ blockoff,
                                                 int* __restrict__ bucket_base,
                                                 int* __restrict__ offs) {
    __shared__ int wsum[4];
    int t = threadIdx.x;
    const int* row = histT + t * NBLK;
    int s = 0;
#pragma unroll 4
    for (int blk = 0; blk < NBLK; ++blk) s += row[blk];
    int incl = wave_incl_scan(s);
    if ((t & 63) == 63) wsum[t >> 6] = incl;
    __syncthreads();
    int add = 0;
    for (int w = 0; w < (t >> 6); ++w) add += wsum[w];
    int excl = incl - s + add;
    bucket_base[t] = excl;
    if (t == 255) bucket_base[256] = excl + s;   // == NE
    int run = excl;
    for (int blk = 0; blk < NBLK; ++blk) {
        blockoff[blk * 256 + t] = run;
        run += row[blk];
    }
    if (t == 0) offs[NN] = NE;
}

__global__ __launch_bounds__(256) void p3_scatter_k(const int* __restrict__ src,
                                                    const int* __restrict__ dst,
                                                    const int* __restrict__ blockoff,
                                                    uint32* __restrict__ ebuf) {
    __shared__ int cur[256];
    int t = threadIdx.x;
    cur[t] = blockoff[blockIdx.x * 256 + t];
    __syncthreads();
    int e0 = blockIdx.x * EBLK;
#pragma unroll
    for (int i = 0; i < EBLK / 256; ++i) {
        int e = e0 + i * 256 + t;
        if (e < NE) {
            int d = dst[e];
            int pos = atomicAdd(&cur[d >> 9], 1);      // LDS atomic
            ebuf[pos] = ((uint32)(d & 511) << 17) | (uint32)src[e];
        }
    }
}

__global__ __launch_bounds__(256) void p4_csr_k(const uint32* __restrict__ ebuf,
                                                const int* __restrict__ bucket_base,
                                                int* __restrict__ offs,
                                                float* __restrict__ dinv,
                                                int* __restrict__ csrc) {
    __shared__ int cntL[512];
    __shared__ int offL[512];
    __shared__ int wsum[4];
    int t = threadIdx.x;
    int bbase = bucket_base[blockIdx.x];
    int bend  = bucket_base[blockIdx.x + 1];
    cntL[t] = 0; cntL[t + 256] = 0;
    __syncthreads();
    for (int e = bbase + t; e < bend; e += 256)
        atomicAdd(&cntL[ebuf[e] >> 17], 1);
    __syncthreads();
    int c0 = cntL[2 * t], c1 = cntL[2 * t + 1];
    int ps = c0 + c1;
    int incl = wave_incl_scan(ps);
    if ((t & 63) == 63) wsum[t >> 6] = incl;
    __syncthreads();
    int add = 0;
    for (int w = 0; w < (t >> 6); ++w) add += wsum[w];
    int excl = incl - ps + add;
    offL[2 * t] = excl;
    offL[2 * t + 1] = excl + c0;
    int n0 = blockIdx.x * 512;
#pragma unroll
    for (int j = 0; j < 2; ++j) {
        int dl = 2 * t + j;
        int node = n0 + dl;
        if (node < NN) {
            offs[node] = bbase + offL[dl];
            dinv[node] = rsqrtf((float)(cntL[dl] + 1));
        }
    }
    __syncthreads();
    cntL[2 * t] = offL[2 * t];          // reuse as cursors
    cntL[2 * t + 1] = offL[2 * t + 1];
    __syncthreads();
    for (int e = bbase + t; e < bend; e += 256) {
        uint32 v = ebuf[e];
        int pos = atomicAdd(&cntL[v >> 17], 1);   // LDS atomic
        csrc[bbase + pos] = (int)(v & 0x1FFFFu);
    }
}

// ---------------- GEMM: HS[N,128](bf16) = dinv * act(X) @ W ----------------
// AFF=0: X is f32 [N,128]. AFF=1: X is packed bf16 rows (64 uints), apply
// relu(sc*x+sh) on load (fused GraphNorm+ReLU). Output pre-scaled by dinv.
// Inner loop: k in quads, ds_read_b128 per row (row pitch 132 f32 = 528 B,
// 16B-aligned), 8 cached W float4 loads, 128 FMAs per quad.

template <int AFF>
__global__ __launch_bounds__(256) void gemm_k(const void* __restrict__ Xv,
                                              const float* __restrict__ W,
                                              const float* __restrict__ par,
                                              const float* __restrict__ dinv,
                                              unsigned short* __restrict__ HS) {
    __shared__ float xs[64][132];
    int t = threadIdx.x;
    int row0 = blockIdx.x * 64;
    for (int i = t; i < 64 * 32; i += 256) {
        int r = i >> 5, c4 = i & 31;
        int row = row0 + r;
        float4 v = make_float4(0.f, 0.f, 0.f, 0.f);
        if (row < NN) {
            if (AFF) {
                uint2 u = ((const uint2*)((const uint32*)Xv + (size_t)row * 64))[c4];
                v.x = bflo(u.x); v.y = bfhi(u.x);
                v.z = bflo(u.y); v.w = bfhi(u.y);
                int c = c4 * 4;
                v.x = fmaxf(0.f, fmaf(par[c + 0], v.x, par[128 + c + 0]));
                v.y = fmaxf(0.f, fmaf(par[c + 1], v.y, par[128 + c + 1]));
                v.z = fmaxf(0.f, fmaf(par[c + 2], v.z, par[128 + c + 2]));
                v.w = fmaxf(0.f, fmaf(par[c + 3], v.w, par[128 + c + 3]));
            } else {
                v = ((const float4*)((const float*)Xv + (size_t)row * 128))[c4];
            }
        }
        *(float4*)&xs[r][c4 * 4] = v;
    }
    __syncthreads();
    int tx = t & 15, ty = t >> 4;      // 16 col-groups x 16 row-groups
    float acc[4][8];
#pragma unroll
    for (int r = 0; r < 4; ++r)
#pragma unroll
        for (int j = 0; j < 8; ++j) acc[r][j] = 0.f;

    for (int k4 = 0; k4 < 32; ++k4) {
        float4 xv[4];
#pragma unroll
        for (int r = 0; r < 4; ++r) xv[r] = *(const float4*)&xs[ty * 4 + r][k4 * 4];
        const float* Wk = W + k4 * 4 * 128 + tx * 8;
        float4 wA0 = *(const float4*)(Wk + 0);
        float4 wA1 = *(const float4*)(Wk + 4);
        float4 wB0 = *(const float4*)(Wk + 128);
        float4 wB1 = *(const float4*)(Wk + 132);
        float4 wC0 = *(const float4*)(Wk + 256);
        float4 wC1 = *(const float4*)(Wk + 260);
        float4 wD0 = *(const float4*)(Wk + 384);
        float4 wD1 = *(const float4*)(Wk + 388);
#pragma unroll
        for (int r = 0; r < 4; ++r) {
            float a = xv[r].x, b = xv[r].y, c = xv[r].z, d = xv[r].w;
            acc[r][0] = fmaf(a, wA0.x, acc[r][0]);
            acc[r][1] = fmaf(a, wA0.y, acc[r][1]);
            acc[r][2] = fmaf(a, wA0.z, acc[r][2]);
            acc[r][3] = fmaf(a, wA0.w, acc[r][3]);
            acc[r][4] = fmaf(a, wA1.x, acc[r][4]);
            acc[r][5] = fmaf(a, wA1.y, acc[r][5]);
            acc[r][6] = fmaf(a, wA1.z, acc[r][6]);
            acc[r][7] = fmaf(a, wA1.w, acc[r][7]);
            acc[r][0] = fmaf(b, wB0.x, acc[r][0]);
            acc[r][1] = fmaf(b, wB0.y, acc[r][1]);
            acc[r][2] = fmaf(b, wB0.z, acc[r][2]);
            acc[r][3] = fmaf(b, wB0.w, acc[r][3]);
            acc[r][4] = fmaf(b, wB1.x, acc[r][4]);
            acc[r][5] = fmaf(b, wB1.y, acc[r][5]);
            acc[r][6] = fmaf(b, wB1.z, acc[r][6]);
            acc[r][7] = fmaf(b, wB1.w, acc[r][7]);
            acc[r][0] = fmaf(c, wC0.x, acc[r][0]);
            acc[r][1] = fmaf(c, wC0.y, acc[r][1]);
            acc[r][2] = fmaf(c, wC0.z, acc[r][2]);
            acc[r][3] = fmaf(c, wC0.w, acc[r][3]);
            acc[r][4] = fmaf(c, wC1.x, acc[r][4]);
            acc[r][5] = fmaf(c, wC1.y, acc[r][5]);
            acc[r][6] = fmaf(c, wC1.z, acc[r][6]);
            acc[r][7] = fmaf(c, wC1.w, acc[r][7]);
            acc[r][0] = fmaf(d, wD0.x, acc[r][0]);
            acc[r][1] = fmaf(d, wD0.y, acc[r][1]);
            acc[r][2] = fmaf(d, wD0.z, acc[r][2]);
            acc[r][3] = fmaf(d, wD0.w, acc[r][3]);
            acc[r][4] = fmaf(d, wD1.x, acc[r][4]);
            acc[r][5] = fmaf(d, wD1.y, acc[r][5]);
            acc[r][6] = fmaf(d, wD1.z, acc[r][6]);
            acc[r][7] = fmaf(d, wD1.w, acc[r][7]);
        }
    }
#pragma unroll
    for (int r = 0; r < 4; ++r) {
        int row = row0 + ty * 4 + r;
        if (row < NN) {
            float d = dinv[row];
            uint4 o;
            o.x = (uint32)f2bf(d * acc[r][0]) | ((uint32)f2bf(d * acc[r][1]) << 16);
            o.y = (uint32)f2bf(d * acc[r][2]) | ((uint32)f2bf(d * acc[r][3]) << 16);
            o.z = (uint32)f2bf(d * acc[r][4]) | ((uint32)f2bf(d * acc[r][5]) << 16);
            o.w = (uint32)f2bf(d * acc[r][6]) | ((uint32)f2bf(d * acc[r][7]) << 16);
            ((uint4*)(HS + (size_t)row * 128))[tx] = o;
        }
    }
}

// ---------------- edge aggregation (atomic-free, CSR by dst, bf16 gather) ---
// hs rows pre-scaled by dinv:
// out[i,c] = dinv[i]*( sum_e hs[src,c] + hs[i,c] ) + bias[c]   (bf16 packed)
// One wave per node; lane owns channels {2*lane, 2*lane+1} via one uint load.
// 8-deep MLP unroll: 8 independent row-gathers in flight per wave.

__global__ __launch_bounds__(256) void aggregate_k(const uint32* __restrict__ hv,
                                                   const int* __restrict__ offs,
                                                   const int* __restrict__ csrc,
                                                   const float* __restrict__ dinv,
                                                   const float* __restrict__ bias,
                                                   uint32* __restrict__ out) {
    int t = threadIdx.x;
    int node = blockIdx.x * 4 + (t >> 6);
    if (node >= NN) return;
    int lane = t & 63;
    int beg = offs[node], end = offs[node + 1];
    float di = dinv[node];
    uint32 sv = hv[(size_t)node * 64 + lane];   // self (pre-scaled)
    float a0 = bflo(sv), a1 = bfhi(sv);
    int e = beg;
    for (; e + 7 < end; e += 8) {
        int s0 = csrc[e + 0], s1 = csrc[e + 1], s2 = csrc[e + 2], s3 = csrc[e + 3];
        int s4 = csrc[e + 4], s5 = csrc[e + 5], s6 = csrc[e + 6], s7 = csrc[e + 7];
        uint32 v0 = hv[(size_t)s0 * 64 + lane];
        uint32 v1 = hv[(size_t)s1 * 64 + lane];
        uint32 v2 = hv[(size_t)s2 * 64 + lane];
        uint32 v3 = hv[(size_t)s3 * 64 + lane];
        uint32 v4 = hv[(size_t)s4 * 64 + lane];
        uint32 v5 = hv[(size_t)s5 * 64 + lane];
        uint32 v6 = hv[(size_t)s6 * 64 + lane];
        uint32 v7 = hv[(size_t)s7 * 64 + lane];
        a0 += ((bflo(v0) + bflo(v1)) + (bflo(v2) + bflo(v3)))
            + ((bflo(v4) + bflo(v5)) + (bflo(v6) + bflo(v7)));
        a1 += ((bfhi(v0) + bfhi(v1)) + (bfhi(v2) + bfhi(v3)))
            + ((bfhi(v4) + bfhi(v5)) + (bfhi(v6) + bfhi(v7)));
    }
    for (; e + 3 < end; e += 4) {
        int s0 = csrc[e + 0], s1 = csrc[e + 1], s2 = csrc[e + 2], s3 = csrc[e + 3];
        uint32 v0 = hv[(size_t)s0 * 64 + lane];
        uint32 v1 = hv[(size_t)s1 * 64 + lane];
        uint32 v2 = hv[(size_t)s2 * 64 + lane];
        uint32 v3 = hv[(size_t)s3 * 64 + lane];
        a0 += (bflo(v0) + bflo(v1)) + (bflo(v2) + bflo(v3));
        a1 += (bfhi(v0) + bfhi(v1)) + (bfhi(v2) + bfhi(v3));
    }
    for (; e < end; ++e) {
        int s0 = csrc[e];
        uint32 v0 = hv[(size_t)s0 * 64 + lane];
        a0 += bflo(v0);
        a1 += bfhi(v0);
    }
    float2 bb = ((const float2*)bias)[lane];
    float o0 = fmaf(di, a0, bb.x);
    float o1 = fmaf(di, a1, bb.y);
    out[(size_t)node * 64 + lane] = (uint32)f2bf(o0) | ((uint32)f2bf(o1) << 16);
}

// ---------------- GraphNorm stats over packed-bf16 activations ------------

__global__ __launch_bounds__(256) void colstats_k(const uint32* __restrict__ A,
                                                  float* __restrict__ stats) {
    __shared__ float4 sh[256];
    int t = threadIdx.x;
    int cp = t & 63;
    float s0 = 0.f, s1 = 0.f, q0 = 0.f, q1 = 0.f;
    for (int r = blockIdx.x * 4 + (t >> 6); r < NN; r += gridDim.x * 4) {
        uint32 u = A[(size_t)r * 64 + cp];
        float v0 = bflo(u), v1 = bfhi(u);
        s0 += v0; s1 += v1;
        q0 = fmaf(v0, v0, q0); q1 = fmaf(v1, v1, q1);
    }
    sh[t] = make_float4(s0, s1, q0, q1);
    __syncthreads();
    if (t < 128) {
        float4 a = sh[t], b = sh[t + 128];
        sh[t] = make_float4(a.x + b.x, a.y + b.y, a.z + b.z, a.w + b.w);
    }
    __syncthreads();
    if (t < 64) {
        float4 a = sh[t], b = sh[t + 64];
        atomicAdd(&stats[2 * cp], a.x + b.x);
        atomicAdd(&stats[2 * cp + 1], a.y + b.y);
        atomicAdd(&stats[128 + 2 * cp], a.z + b.z);
        atomicAdd(&stats[128 + 2 * cp + 1], a.w + b.w);
    }
}

__global__ void gnparams_k(const float* __restrict__ stats, const float* __restrict__ w,
                           const float* __restrict__ b, const float* __restrict__ a,
                           float* __restrict__ par) {
    int c = threadIdx.x;
    if (c < 128) {
        float m = stats[c] * (1.0f / NN);
        float ex2 = stats[128 + c] * (1.0f / NN);
        float ac = a[c];
        // var of (x - a*m): E[x^2] - 2*a*m^2 + a^2*m^2
        float var = ex2 - 2.0f * ac * m * m + ac * ac * m * m;
        float sc = w[c] * rsqrtf(var + 1e-5f);
        par[c] = sc;                       // scale
        par[128 + c] = b[c] - sc * ac * m; // shift
    }
}

// ---------------- head: out = [x, relu(gn2(x2))] @ Wh + bh ----------------

__global__ __launch_bounds__(256) void final_k(const float* __restrict__ x,
                                               const uint32* __restrict__ x2,
                                               const float* __restrict__ par,
                                               const float* __restrict__ Wh,
                                               const float* __restrict__ bh,
                                               float* __restrict__ out) {
    __shared__ float wl[256][16];
    int t = threadIdx.x;
    for (int i = t; i < 256 * 16; i += 256) wl[i >> 4][i & 15] = Wh[i];
    __syncthreads();
    int row = blockIdx.x * 16 + (t >> 4);
    int o = t & 15;
    if (row >= NN) return;
    const float4* xp = (const float4*)(x + (size_t)row * 128);
    const uint4* x2p = (const uint4*)(x2 + (size_t)row * 64);
    float acc = bh[o];
#pragma unroll
    for (int k4 = 0; k4 < 32; ++k4) {
        float4 v = xp[k4];
        acc = fmaf(v.x, wl[k4 * 4 + 0][o], acc);
        acc = fmaf(v.y, wl[k4 * 4 + 1][o], acc);
        acc = fmaf(v.z, wl[k4 * 4 + 2][o], acc);
        acc = fmaf(v.w, wl[k4 * 4 + 3][o], acc);
    }
#pragma unroll
    for (int k8 = 0; k8 < 16; ++k8) {
        uint4 u = x2p[k8];
        int c = k8 * 8;
        float v0 = bflo(u.x), v1 = bfhi(u.x);
        float v2 = bflo(u.y), v3 = bfhi(u.y);
        float v4 = bflo(u.z), v5 = bfhi(u.z);
        float v6 = bflo(u.w), v7 = bfhi(u.w);
        v0 = fmaxf(0.f, fmaf(par[c + 0], v0, par[128 + c + 0]));
        v1 = fmaxf(0.f, fmaf(par[c + 1], v1, par[128 + c + 1]));
        v2 = fmaxf(0.f, fmaf(par[c + 2], v2, par[128 + c + 2]));
        v3 = fmaxf(0.f, fmaf(par[c + 3], v3, par[128 + c + 3]));
        v4 = fmaxf(0.f, fmaf(par[c + 4], v4, par[128 + c + 4]));
        v5 = fmaxf(0.f, fmaf(par[c + 5], v5, par[128 + c + 5]));
        v6 = fmaxf(0.f, fmaf(par[c + 6], v6, par[128 + c + 6]));
        v7 = fmaxf(0.f, fmaf(par[c + 7], v7, par[128 + c + 7]));
        acc = fmaf(v0, wl[128 + c + 0][o], acc);
        acc = fmaf(v1, wl[128 + c + 1][o], acc);
        acc = fmaf(v2, wl[128 + c + 2][o], acc);
        acc = fmaf(v3, wl[128 + c + 3][o], acc);
        acc = fmaf(v4, wl[128 + c + 4][o], acc);
        acc = fmaf(v5, wl[128 + c + 5][o], acc);
        acc = fmaf(v6, wl[128 + c + 6][o], acc);
        acc = fmaf(v7, wl[128 + c + 7][o], acc);
    }
    out[(size_t)row * 16 + o] = acc;
}

// ---------------- launch ----------------

extern "C" void kernel_launch(void* const* d_in, const int* in_sizes, int n_in,
                              void* d_out, int out_size, void* d_ws, size_t ws_size,
                              hipStream_t stream) {
    const float* x   = (const float*)d_in[0];
    const int*   ei  = (const int*)d_in[1];
    const float* W1  = (const float*)d_in[2];
    const float* b1  = (const float*)d_in[3];
    const float* g1w = (const float*)d_in[4];
    const float* g1b = (const float*)d_in[5];
    const float* g1a = (const float*)d_in[6];
    const float* W2  = (const float*)d_in[7];
    const float* b2  = (const float*)d_in[8];
    const float* g2w = (const float*)d_in[9];
    const float* g2b = (const float*)d_in[10];
    const float* g2a = (const float*)d_in[11];
    const float* Wh  = (const float*)d_in[12];
    const float* bh  = (const float*)d_in[13];
    const int* srcp = ei;        // edge_index row 0
    const int* dstp = ei + NE;   // edge_index row 1
    float* out = (float*)d_out;

    char* p = (char*)d_ws;
    auto take = [&](size_t bytes) { char* r = p; p += (bytes + 255) & ~(size_t)255; return r; };
    int*   histT  = (int*)take((size_t)256 * NBLK * 4);
    int*   blockoff = (int*)take((size_t)NBLK * 256 * 4);
    int*   bucket_base = (int*)take(257 * 4);
    uint32* ebuf  = (uint32*)take((size_t)NE * 4);
    int*   offs   = (int*)take((size_t)(NN + 1) * 4);
    int*   csrc   = (int*)take((size_t)NE * 4);
    float* dinv   = (float*)take((size_t)NN * 4);
    float* stats1 = (float*)take(256 * 4);
    float* stats2 = (float*)take(256 * 4);
    float* par1   = (float*)take(256 * 4);
    float* par2   = (float*)take(256 * 4);
    unsigned short* bufH = (unsigned short*)take((size_t)NN * 128 * 2);  // bf16
    uint32* bufA  = (uint32*)take((size_t)NN * 64 * 4);                  // bf16 packed

    hipMemsetAsync(stats1, 0, 256 * 4, stream);
    hipMemsetAsync(stats2, 0, 256 * 4, stream);

    // CSR build (atomic-free, streaming)
    p1_hist_k<<<NBLK, 256, 0, stream>>>(dstp, histT);
    p2_scan_k<<<1, 256, 0, stream>>>(histT, blockoff, bucket_base, offs);
    p3_scatter_k<<<NBLK, 256, 0, stream>>>(srcp, dstp, blockoff, ebuf);
    p4_csr_k<<<NBUCK, 256, 0, stream>>>(ebuf, bucket_base, offs, dinv, csrc);

    // layer 1: h1 = dinv * (x @ W1) (bf16), aggregate, stats
    gemm_k<0><<<(NN + 63) / 64, 256, 0, stream>>>(x, W1, nullptr, dinv, bufH);
    aggregate_k<<<(NN + 3) / 4, 256, 0, stream>>>((const uint32*)bufH, offs, csrc, dinv, b1, bufA);
    colstats_k<<<512, 256, 0, stream>>>(bufA, stats1);
    gnparams_k<<<1, 128, 0, stream>>>(stats1, g1w, g1b, g1a, par1);

    // layer 2: h2 = dinv * (relu(gn1(bufA)) @ W2), aggregate, stats
    gemm_k<1><<<(NN + 63) / 64, 256, 0, stream>>>(bufA, W2, par1, dinv, bufH);
    aggregate_k<<<(NN + 3) / 4, 256, 0, stream>>>((const uint32*)bufH, offs, csrc, dinv, b2, bufA);
    colstats_k<<<512, 256, 0, stream>>>(bufA, stats2);
    gnparams_k<<<1, 128, 0, stream>>>(stats2, g2w, g2b, g2a, par2);

    // head: out = [x, relu(gn2(bufA))] @ Wh + bh (gn2 fused on load)
    final_k<<<(NN + 15) / 16, 256, 0, stream>>>(x, bufA, par2, Wh, bh, out);
}

// Round 8
// 363.639 us; speedup vs baseline: 3.7870x; 1.3306x over previous
//
#include <hip/hip_runtime.h>

#define NN 100000
#define NE 1600000

#define EBLK 4096
#define NBLK 391            // ceil(NE/EBLK)
#define NBUCK 196           // ceil(NN/512), bucket = dst>>9

typedef unsigned int uint32;
typedef __attribute__((ext_vector_type(8))) short bf16x8;
typedef __attribute__((ext_vector_type(4))) float f32x4;

__device__ inline unsigned short f2bf(float f) {
    uint32 u = __float_as_uint(f);
    u += 0x7FFFu + ((u >> 16) & 1u);      // round to nearest even
    return (unsigned short)(u >> 16);
}
__device__ inline float bflo(uint32 v) { return __uint_as_float(v << 16); }
__device__ inline float bfhi(uint32 v) { return __uint_as_float(v & 0xFFFF0000u); }

__device__ inline int wave_incl_scan(int v) {   // 64-lane inclusive scan
#pragma unroll
    for (int d = 1; d < 64; d <<= 1) {
        int u = __shfl_up(v, d, 64);
        if ((threadIdx.x & 63) >= (unsigned)d) v += u;
    }
    return v;
}

// ---------------- CSR build, atomic-free (bucketed) ----------------

__global__ __launch_bounds__(256) void p1_hist_k(const int* __restrict__ dst,
                                                 int* __restrict__ histT) {
    __shared__ int h[256];
    int t = threadIdx.x;
    h[t] = 0;
    __syncthreads();
    int e0 = blockIdx.x * EBLK;
#pragma unroll
    for (int i = 0; i < EBLK / 256; ++i) {
        int e = e0 + i * 256 + t;
        if (e < NE) atomicAdd(&h[dst[e] >> 9], 1);
    }
    __syncthreads();
    histT[t * NBLK + blockIdx.x] = h[t];   // histT[bucket][blk]
}

// p2a: one block per bucket — exclusive scan of its 391 per-block counts.

__global__ __launch_bounds__(256) void p2a_k(const int* __restrict__ histT,
                                             int* __restrict__ boff2,
                                             int* __restrict__ btot) {
    __shared__ int ws[4];
    __shared__ int ws2[4];
    int b = blockIdx.x, t = threadIdx.x;
    const int* row = histT + (size_t)b * NBLK;
    int v0 = row[t];
    int i0 = wave_incl_scan(v0);
    if ((t & 63) == 63) ws[t >> 6] = i0;
    __syncthreads();
    int add = 0;
    for (int w = 0; w < (t >> 6); ++w) add += ws[w];
    boff2[(size_t)b * NBLK + t] = i0 - v0 + add;
    int tot0 = ws[0] + ws[1] + ws[2] + ws[3];
    int idx = 256 + t;
    int v1 = (idx < NBLK) ? row[idx] : 0;
    int i1 = wave_incl_scan(v1);
    if ((t & 63) == 63) ws2[t >> 6] = i1;
    __syncthreads();
    int add2 = 0;
    for (int w = 0; w < (t >> 6); ++w) add2 += ws2[w];
    if (idx < NBLK) boff2[(size_t)b * NBLK + idx] = tot0 + i1 - v1 + add2;
    if (t == 0) btot[b] = tot0 + ws2[0] + ws2[1] + ws2[2] + ws2[3];
}

// p2b: scan 256 bucket totals -> bucket_base.

__global__ __launch_bounds__(256) void p2b_k(const int* __restrict__ btot,
                                             int* __restrict__ bucket_base,
                                             int* __restrict__ offs) {
    __shared__ int ws[4];
    int t = threadIdx.x;
    int v = btot[t];
    int incl = wave_incl_scan(v);
    if ((t & 63) == 63) ws[t >> 6] = incl;
    __syncthreads();
    int add = 0;
    for (int w = 0; w < (t >> 6); ++w) add += ws[w];
    int excl = incl - v + add;
    bucket_base[t] = excl;
    if (t == 255) bucket_base[256] = excl + v;   // == NE
    if (t == 0) offs[NN] = NE;
}

__global__ __launch_bounds__(256) void p3_scatter_k(const int* __restrict__ src,
                                                    const int* __restrict__ dst,
                                                    const int* __restrict__ boff2,
                                                    const int* __restrict__ bucket_base,
                                                    uint32* __restrict__ ebuf) {
    __shared__ int cur[256];
    int t = threadIdx.x;
    cur[t] = bucket_base[t] + boff2[(size_t)t * NBLK + blockIdx.x];
    __syncthreads();
    int e0 = blockIdx.x * EBLK;
#pragma unroll
    for (int i = 0; i < EBLK / 256; ++i) {
        int e = e0 + i * 256 + t;
        if (e < NE) {
            int d = dst[e];
            int pos = atomicAdd(&cur[d >> 9], 1);      // LDS atomic
            ebuf[pos] = ((uint32)(d & 511) << 17) | (uint32)src[e];
        }
    }
}

__global__ __launch_bounds__(256) void p4_csr_k(const uint32* __restrict__ ebuf,
                                                const int* __restrict__ bucket_base,
                                                int* __restrict__ offs,
                                                float* __restrict__ dinv,
                                                int* __restrict__ csrc) {
    __shared__ int cntL[512];
    __shared__ int offL[512];
    __shared__ int wsum[4];
    int t = threadIdx.x;
    int bbase = bucket_base[blockIdx.x];
    int bend  = bucket_base[blockIdx.x + 1];
    cntL[t] = 0; cntL[t + 256] = 0;
    __syncthreads();
    for (int e = bbase + t; e < bend; e += 256)
        atomicAdd(&cntL[ebuf[e] >> 17], 1);
    __syncthreads();
    int c0 = cntL[2 * t], c1 = cntL[2 * t + 1];
    int ps = c0 + c1;
    int incl = wave_incl_scan(ps);
    if ((t & 63) == 63) wsum[t >> 6] = incl;
    __syncthreads();
    int add = 0;
    for (int w = 0; w < (t >> 6); ++w) add += wsum[w];
    int excl = incl - ps + add;
    offL[2 * t] = excl;
    offL[2 * t + 1] = excl + c0;
    int n0 = blockIdx.x * 512;
#pragma unroll
    for (int j = 0; j < 2; ++j) {
        int dl = 2 * t + j;
        int node = n0 + dl;
        if (node < NN) {
            offs[node] = bbase + offL[dl];
            dinv[node] = rsqrtf((float)(cntL[dl] + 1));
        }
    }
    __syncthreads();
    cntL[2 * t] = offL[2 * t];          // reuse as cursors
    cntL[2 * t + 1] = offL[2 * t + 1];
    __syncthreads();
    for (int e = bbase + t; e < bend; e += 256) {
        uint32 v = ebuf[e];
        int pos = atomicAdd(&cntL[v >> 17], 1);   // LDS atomic
        csrc[bbase + pos] = (int)(v & 0x1FFFFu);
    }
}

// -------- W prep: Wt[col][k] bf16-packed (uint = 2 consecutive k) --------

__global__ __launch_bounds__(256) void wprep_k(const float* __restrict__ W,
                                               uint32* __restrict__ Wt) {
    int id = blockIdx.x * 256 + threadIdx.x;   // 8192 uints
    int col = id >> 6, ku = id & 63;
    float a = W[(2 * ku) * 128 + col];
    float b = W[(2 * ku + 1) * 128 + col];
    Wt[id] = (uint32)f2bf(a) | ((uint32)f2bf(b) << 16);
}

// ---------------- MFMA GEMM: HS[N,128](bf16) = dinv * act(X) @ W ----------
// AFF=0: X f32 [N,128].  AFF=1: X packed bf16, apply relu(sc*x+sh) on load.
// Block: 256 thr / 4 waves, tile 64 rows x 128 cols, K=128 in 4 steps of 32.
// LDS: A [64][136] bf16 (17408 B) + Bt [128][136] bf16 (34816 B) = 52224 B.
// Fragment mapping (16x16x32_bf16): A lane l holds A[l&15][8*(l>>4)+j];
// B lane l holds B[8*(l>>4)+j][l&15]; D col=lane&15, row=(lane>>4)*4+reg.

template <int AFF>
__global__ __launch_bounds__(256) void gemm_k(const void* __restrict__ Xv,
                                              const uint32* __restrict__ Wt,
                                              const float* __restrict__ par,
                                              const float* __restrict__ dinv,
                                              uint32* __restrict__ HS) {
    __shared__ __align__(16) char lds[52224];
    const int APITCH = 272;               // bytes per A/B row (136 bf16)
    char* Ab = lds;
    char* Bb = lds + 17408;
    int t = threadIdx.x;
    int row0 = blockIdx.x * 64;

    // stage Bt: 128 rows x 16 uint4
    {
        uint4* src = (uint4*)Wt;
#pragma unroll
        for (int i = 0; i < 8; ++i) {
            int idx4 = i * 256 + t;          // 2048 uint4
            int r = idx4 >> 4, cu = idx4 & 15;
            *(uint4*)(Bb + r * APITCH + cu * 16) = src[r * 16 + cu];
        }
    }
    // stage A: 64 rows x 128 bf16
#pragma unroll
    for (int i = 0; i < 8; ++i) {
        int idx = i * 256 + t;               // 2048 quads of channels
        int r = idx >> 5, c4 = idx & 31;
        int row = row0 + r;
        float4 v = make_float4(0.f, 0.f, 0.f, 0.f);
        if (row < NN) {
            if (AFF) {
                uint2 u = *((const uint2*)((const uint32*)Xv + (size_t)row * 64) + c4);
                v.x = bflo(u.x); v.y = bfhi(u.x);
                v.z = bflo(u.y); v.w = bfhi(u.y);
                int c = c4 * 4;
                v.x = fmaxf(0.f, fmaf(par[c + 0], v.x, par[128 + c + 0]));
                v.y = fmaxf(0.f, fmaf(par[c + 1], v.y, par[128 + c + 1]));
                v.z = fmaxf(0.f, fmaf(par[c + 2], v.z, par[128 + c + 2]));
                v.w = fmaxf(0.f, fmaf(par[c + 3], v.w, par[128 + c + 3]));
            } else {
                v = *((const float4*)((const float*)Xv + (size_t)row * 128) + c4);
            }
        }
        uint32 o0 = (uint32)f2bf(v.x) | ((uint32)f2bf(v.y) << 16);
        uint32 o1 = (uint32)f2bf(v.z) | ((uint32)f2bf(v.w) << 16);
        uint2 o; o.x = o0; o.y = o1;
        *(uint2*)(Ab + r * APITCH + c4 * 8) = o;
    }
    __syncthreads();

    int w = t >> 6, lane = t & 63;
    int l15 = lane & 15, l4 = lane >> 4;
    const char* aptr = Ab + (w * 16 + l15) * APITCH + l4 * 16;
    const char* bptr = Bb + l15 * APITCH + l4 * 16;
    f32x4 acc[8];
#pragma unroll
    for (int n = 0; n < 8; ++n)
#pragma unroll
        for (int j = 0; j < 4; ++j) acc[n][j] = 0.f;

#pragma unroll
    for (int ks = 0; ks < 4; ++ks) {
        bf16x8 a = *(const bf16x8*)(aptr + ks * 64);
#pragma unroll
        for (int n = 0; n < 8; ++n) {
            bf16x8 b = *(const bf16x8*)(bptr + n * 16 * APITCH + ks * 64);
            acc[n] = __builtin_amdgcn_mfma_f32_16x16x32_bf16(a, b, acc[n], 0, 0, 0);
        }
    }

    // epilogue: dinv scale -> bf16 -> LDS (reuse A region) -> coalesced store
    float dv[4];
    int rbase = row0 + w * 16 + l4 * 4;
#pragma unroll
    for (int j = 0; j < 4; ++j)
        dv[j] = (rbase + j < NN) ? dinv[rbase + j] : 0.f;
    unsigned short* ep = (unsigned short*)Ab;
#pragma unroll
    for (int n = 0; n < 8; ++n)
#pragma unroll
        for (int j = 0; j < 4; ++j)
            ep[(w * 16 + l4 * 4 + j) * 136 + n * 16 + l15] = f2bf(dv[j] * acc[n][j]);
    __syncthreads();
    int srow = lane >> 2, seg = lane & 3;
    int grow = row0 + w * 16 + srow;
    if (grow < NN) {
        const char* lp = Ab + (w * 16 + srow) * APITCH + seg * 64;
        uint4* gp = (uint4*)(HS + (size_t)grow * 64 + seg * 16);
#pragma unroll
        for (int i = 0; i < 4; ++i)
            gp[i] = *(const uint4*)(lp + i * 16);
    }
}

// ---------------- edge aggregation (atomic-free, CSR by dst, bf16 gather) ---
// hs rows pre-scaled by dinv:
// out[i,c] = dinv[i]*( sum_e hs[src,c] + hs[i,c] ) + bias[c]   (bf16 packed)
// One wave per node; lane owns channels {2*lane, 2*lane+1} via one uint load.
// 8-deep MLP unroll: 8 independent row-gathers in flight per wave.

__global__ __launch_bounds__(256) void aggregate_k(const uint32* __restrict__ hv,
                                                   const int* __restrict__ offs,
                                                   const int* __restrict__ csrc,
                                                   const float* __restrict__ dinv,
                                                   const float* __restrict__ bias,
                                                   uint32* __restrict__ out) {
    int t = threadIdx.x;
    int node = blockIdx.x * 4 + (t >> 6);
    if (node >= NN) return;
    int lane = t & 63;
    int beg = offs[node], end = offs[node + 1];
    float di = dinv[node];
    uint32 sv = hv[(size_t)node * 64 + lane];   // self (pre-scaled)
    float a0 = bflo(sv), a1 = bfhi(sv);
    int e = beg;
    for (; e + 7 < end; e += 8) {
        int s0 = csrc[e + 0], s1 = csrc[e + 1], s2 = csrc[e + 2], s3 = csrc[e + 3];
        int s4 = csrc[e + 4], s5 = csrc[e + 5], s6 = csrc[e + 6], s7 = csrc[e + 7];
        uint32 v0 = hv[(size_t)s0 * 64 + lane];
        uint32 v1 = hv[(size_t)s1 * 64 + lane];
        uint32 v2 = hv[(size_t)s2 * 64 + lane];
        uint32 v3 = hv[(size_t)s3 * 64 + lane];
        uint32 v4 = hv[(size_t)s4 * 64 + lane];
        uint32 v5 = hv[(size_t)s5 * 64 + lane];
        uint32 v6 = hv[(size_t)s6 * 64 + lane];
        uint32 v7 = hv[(size_t)s7 * 64 + lane];
        a0 += ((bflo(v0) + bflo(v1)) + (bflo(v2) + bflo(v3)))
            + ((bflo(v4) + bflo(v5)) + (bflo(v6) + bflo(v7)));
        a1 += ((bfhi(v0) + bfhi(v1)) + (bfhi(v2) + bfhi(v3)))
            + ((bfhi(v4) + bfhi(v5)) + (bfhi(v6) + bfhi(v7)));
    }
    for (; e + 3 < end; e += 4) {
        int s0 = csrc[e + 0], s1 = csrc[e + 1], s2 = csrc[e + 2], s3 = csrc[e + 3];
        uint32 v0 = hv[(size_t)s0 * 64 + lane];
        uint32 v1 = hv[(size_t)s1 * 64 + lane];
        uint32 v2 = hv[(size_t)s2 * 64 + lane];
        uint32 v3 = hv[(size_t)s3 * 64 + lane];
        a0 += (bflo(v0) + bflo(v1)) + (bflo(v2) + bflo(v3));
        a1 += (bfhi(v0) + bfhi(v1)) + (bfhi(v2) + bfhi(v3));
    }
    for (; e < end; ++e) {
        int s0 = csrc[e];
        uint32 v0 = hv[(size_t)s0 * 64 + lane];
        a0 += bflo(v0);
        a1 += bfhi(v0);
    }
    float2 bb = ((const float2*)bias)[lane];
    float o0 = fmaf(di, a0, bb.x);
    float o1 = fmaf(di, a1, bb.y);
    out[(size_t)node * 64 + lane] = (uint32)f2bf(o0) | ((uint32)f2bf(o1) << 16);
}

// ---------------- GraphNorm stats over packed-bf16 activations ------------

__global__ __launch_bounds__(256) void colstats_k(const uint32* __restrict__ A,
                                                  float* __restrict__ stats) {
    __shared__ float4 sh[256];
    int t = threadIdx.x;
    int cp = t & 63;
    float s0 = 0.f, s1 = 0.f, q0 = 0.f, q1 = 0.f;
    for (int r = blockIdx.x * 4 + (t >> 6); r < NN; r += gridDim.x * 4) {
        uint32 u = A[(size_t)r * 64 + cp];
        float v0 = bflo(u), v1 = bfhi(u);
        s0 += v0; s1 += v1;
        q0 = fmaf(v0, v0, q0); q1 = fmaf(v1, v1, q1);
    }
    sh[t] = make_float4(s0, s1, q0, q1);
    __syncthreads();
    if (t < 128) {
        float4 a = sh[t], b = sh[t + 128];
        sh[t] = make_float4(a.x + b.x, a.y + b.y, a.z + b.z, a.w + b.w);
    }
    __syncthreads();
    if (t < 64) {
        float4 a = sh[t], b = sh[t + 64];
        atomicAdd(&stats[2 * cp], a.x + b.x);
        atomicAdd(&stats[2 * cp + 1], a.y + b.y);
        atomicAdd(&stats[128 + 2 * cp], a.z + b.z);
        atomicAdd(&stats[128 + 2 * cp + 1], a.w + b.w);
    }
}

__global__ void gnparams_k(const float* __restrict__ stats, const float* __restrict__ w,
                           const float* __restrict__ b, const float* __restrict__ a,
                           float* __restrict__ par) {
    int c = threadIdx.x;
    if (c < 128) {
        float m = stats[c] * (1.0f / NN);
        float ex2 = stats[128 + c] * (1.0f / NN);
        float ac = a[c];
        // var of (x - a*m): E[x^2] - 2*a*m^2 + a^2*m^2
        float var = ex2 - 2.0f * ac * m * m + ac * ac * m * m;
        float sc = w[c] * rsqrtf(var + 1e-5f);
        par[c] = sc;                       // scale
        par[128 + c] = b[c] - sc * ac * m; // shift
    }
}

// ---------------- head: out = [x, relu(gn2(x2))] @ Wh + bh ----------------

__global__ __launch_bounds__(256) void final_k(const float* __restrict__ x,
                                               const uint32* __restrict__ x2,
                                               const float* __restrict__ par,
                                               const float* __restrict__ Wh,
                                               const float* __restrict__ bh,
                                               float* __restrict__ out) {
    __shared__ float wl[256][16];
    int t = threadIdx.x;
    for (int i = t; i < 256 * 16; i += 256) wl[i >> 4][i & 15] = Wh[i];
    __syncthreads();
    int row = blockIdx.x * 16 + (t >> 4);
    int o = t & 15;
    if (row >= NN) return;
    const float4* xp = (const float4*)(x + (size_t)row * 128);
    const uint4* x2p = (const uint4*)(x2 + (size_t)row * 64);
    float acc = bh[o];
#pragma unroll
    for (int k4 = 0; k4 < 32; ++k4) {
        float4 v = xp[k4];
        acc = fmaf(v.x, wl[k4 * 4 + 0][o], acc);
        acc = fmaf(v.y, wl[k4 * 4 + 1][o], acc);
        acc = fmaf(v.z, wl[k4 * 4 + 2][o], acc);
        acc = fmaf(v.w, wl[k4 * 4 + 3][o], acc);
    }
#pragma unroll
    for (int k8 = 0; k8 < 16; ++k8) {
        uint4 u = x2p[k8];
        int c = k8 * 8;
        float v0 = bflo(u.x), v1 = bfhi(u.x);
        float v2 = bflo(u.y), v3 = bfhi(u.y);
        float v4 = bflo(u.z), v5 = bfhi(u.z);
        float v6 = bflo(u.w), v7 = bfhi(u.w);
        v0 = fmaxf(0.f, fmaf(par[c + 0], v0, par[128 + c + 0]));
        v1 = fmaxf(0.f, fmaf(par[c + 1], v1, par[128 + c + 1]));
        v2 = fmaxf(0.f, fmaf(par[c + 2], v2, par[128 + c + 2]));
        v3 = fmaxf(0.f, fmaf(par[c + 3], v3, par[128 + c + 3]));
        v4 = fmaxf(0.f, fmaf(par[c + 4], v4, par[128 + c + 4]));
        v5 = fmaxf(0.f, fmaf(par[c + 5], v5, par[128 + c + 5]));
        v6 = fmaxf(0.f, fmaf(par[c + 6], v6, par[128 + c + 6]));
        v7 = fmaxf(0.f, fmaf(par[c + 7], v7, par[128 + c + 7]));
        acc = fmaf(v0, wl[128 + c + 0][o], acc);
        acc = fmaf(v1, wl[128 + c + 1][o], acc);
        acc = fmaf(v2, wl[128 + c + 2][o], acc);
        acc = fmaf(v3, wl[128 + c + 3][o], acc);
        acc = fmaf(v4, wl[128 + c + 4][o], acc);
        acc = fmaf(v5, wl[128 + c + 5][o], acc);
        acc = fmaf(v6, wl[128 + c + 6][o], acc);
        acc = fmaf(v7, wl[128 + c + 7][o], acc);
    }
    out[(size_t)row * 16 + o] = acc;
}

// ---------------- launch ----------------

extern "C" void kernel_launch(void* const* d_in, const int* in_sizes, int n_in,
                              void* d_out, int out_size, void* d_ws, size_t ws_size,
                              hipStream_t stream) {
    const float* x   = (const float*)d_in[0];
    const int*   ei  = (const int*)d_in[1];
    const float* W1  = (const float*)d_in[2];
    const float* b1  = (const float*)d_in[3];
    const float* g1w = (const float*)d_in[4];
    const float* g1b = (const float*)d_in[5];
    const float* g1a = (const float*)d_in[6];
    const float* W2  = (const float*)d_in[7];
    const float* b2  = (const float*)d_in[8];
    const float* g2w = (const float*)d_in[9];
    const float* g2b = (const float*)d_in[10];
    const float* g2a = (const float*)d_in[11];
    const float* Wh  = (const float*)d_in[12];
    const float* bh  = (const float*)d_in[13];
    const int* srcp = ei;        // edge_index row 0
    const int* dstp = ei + NE;   // edge_index row 1
    float* out = (float*)d_out;

    char* p = (char*)d_ws;
    auto take = [&](size_t bytes) { char* r = p; p += (bytes + 255) & ~(size_t)255; return r; };
    int*   histT  = (int*)take((size_t)256 * NBLK * 4);
    int*   boff2  = (int*)take((size_t)256 * NBLK * 4);
    int*   btot   = (int*)take(256 * 4);
    int*   bucket_base = (int*)take(257 * 4);
    uint32* ebuf  = (uint32*)take((size_t)NE * 4);
    int*   offs   = (int*)take((size_t)(NN + 1) * 4);
    int*   csrc   = (int*)take((size_t)NE * 4);
    float* dinv   = (float*)take((size_t)NN * 4);
    float* stats1 = (float*)take(256 * 4);
    float* stats2 = (float*)take(256 * 4);
    float* par1   = (float*)take(256 * 4);
    float* par2   = (float*)take(256 * 4);
    uint32* wt1   = (uint32*)take((size_t)128 * 64 * 4);   // bf16 W1^T
    uint32* wt2   = (uint32*)take((size_t)128 * 64 * 4);   // bf16 W2^T
    uint32* bufH  = (uint32*)take((size_t)NN * 64 * 4);    // bf16 packed
    uint32* bufA  = (uint32*)take((size_t)NN * 64 * 4);    // bf16 packed

    hipMemsetAsync(stats1, 0, 256 * 4, stream);
    hipMemsetAsync(stats2, 0, 256 * 4, stream);

    // CSR build (atomic-free, streaming)
    p1_hist_k<<<NBLK, 256, 0, stream>>>(dstp, histT);
    p2a_k<<<256, 256, 0, stream>>>(histT, boff2, btot);
    p2b_k<<<1, 256, 0, stream>>>(btot, bucket_base, offs);
    p3_scatter_k<<<NBLK, 256, 0, stream>>>(srcp, dstp, boff2, bucket_base, ebuf);
    p4_csr_k<<<NBUCK, 256, 0, stream>>>(ebuf, bucket_base, offs, dinv, csrc);

    // weight prep (bf16 transpose)
    wprep_k<<<32, 256, 0, stream>>>(W1, wt1);
    wprep_k<<<32, 256, 0, stream>>>(W2, wt2);

    // layer 1: h1 = dinv * (x @ W1) (bf16 MFMA), aggregate, stats
    gemm_k<0><<<(NN + 63) / 64, 256, 0, stream>>>(x, wt1, nullptr, dinv, bufH);
    aggregate_k<<<(NN + 3) / 4, 256, 0, stream>>>(bufH, offs, csrc, dinv, b1, bufA);
    colstats_k<<<512, 256, 0, stream>>>(bufA, stats1);
    gnparams_k<<<1, 128, 0, stream>>>(stats1, g1w, g1b, g1a, par1);

    // layer 2: h2 = dinv * (relu(gn1(bufA)) @ W2), aggregate, stats
    gemm_k<1><<<(NN + 63) / 64, 256, 0, stream>>>(bufA, wt2, par1, dinv, bufH);
    aggregate_k<<<(NN + 3) / 4, 256, 0, stream>>>(bufH, offs, csrc, dinv, b2, bufA);
    colstats_k<<<512, 256, 0, stream>>>(bufA, stats2);
    gnparams_k<<<1, 128, 0, stream>>>(stats2, g2w, g2b, g2a, par2);

    // head: out = [x, relu(gn2(bufA))] @ Wh + bh (gn2 fused on load)
    final_k<<<(NN + 15) / 16, 256, 0, stream>>>(x, bufA, par2, Wh, bh, out);
}